// Round 2
// baseline (4123.764 us; speedup 1.0000x reference)
//
#include <hip/hip_runtime.h>

#define TDIM 256
#define BDIM 256
#define MTB (TDIM*BDIM)   // 65536 rows

typedef unsigned int uint;
typedef unsigned short ushort;

// ---------- bf16 helpers ----------
__device__ __forceinline__ ushort f2bf(float x) {
    uint b = __float_as_uint(x);
    b = b + 0x7FFFu + ((b >> 16) & 1u);      // RNE
    return (ushort)(b >> 16);
}
__device__ __forceinline__ float bfu(ushort u) { return __uint_as_float(((uint)u) << 16); }
__device__ __forceinline__ float bf_lo(uint u) { return __uint_as_float(u << 16); }
__device__ __forceinline__ float bf_hi(uint u) { return __uint_as_float(u & 0xFFFF0000u); }

// typed 4-element load/store (fp32 or bf16), always fp32 in registers
__device__ __forceinline__ float4 ld4(const float* p) { return *(const float4*)p; }
__device__ __forceinline__ float4 ld4(const ushort* p) {
    ushort4 u = *(const ushort4*)p;
    float4 v; v.x = bfu(u.x); v.y = bfu(u.y); v.z = bfu(u.z); v.w = bfu(u.w);
    return v;
}
__device__ __forceinline__ void st4(float* p, float4 v) { *(float4*)p = v; }
__device__ __forceinline__ void st4(ushort* p, float4 v) {
    ushort4 u; u.x = f2bf(v.x); u.y = f2bf(v.y); u.z = f2bf(v.z); u.w = f2bf(v.w);
    *(ushort4*)p = u;
}

enum { E_BIAS=1, E_RELU=2, E_ACC=4, E_RES=8, E_PE=16, E_MASKA=32 };

// ---------- generic C = A @ W^T GEMM, 64x64x16 tiles, 4x4 microtile ----------
// A: [M,K] (lda), W: [N,K] fp32 (ldw), C: [M,N] (ldc). blockIdx.z batch strides.
template<int EPI, typename AT, typename RT, typename CT>
__global__ __launch_bounds__(256) void gemm_nt(
    int M, int N, int K,
    const AT* __restrict__ A, int lda, int batchA,
    const float* __restrict__ W, int ldw, int batchW,
    CT* __restrict__ C, int ldc, int batchC,
    const float* __restrict__ bias,
    const RT* __restrict__ res,
    const float* __restrict__ pe,
    const int* __restrict__ seqlen)
{
    __shared__ float As[16][68];
    __shared__ float Ws[16][68];
    A += (size_t)blockIdx.z * batchA;
    W += (size_t)blockIdx.z * batchW;
    C += (size_t)blockIdx.z * batchC;
    const int m0 = blockIdx.y * 64, n0 = blockIdx.x * 64;
    const int tid = threadIdx.x;
    const int lr = tid >> 2;            // 0..63
    const int lc = (tid & 3) << 2;      // 0,4,8,12
    const int ti = tid >> 4;            // 0..15
    const int tj = tid & 15;            // 0..15

    bool avalid = true;
    if (EPI & E_MASKA) {
        int m = m0 + lr;                 // m = t*256 + b
        avalid = ((m >> 8) < seqlen[m & 255]);
    }
    const AT* Aptr = A + (size_t)(m0 + lr) * lda + lc;
    const float* Wptr = W + (size_t)(n0 + lr) * ldw + lc;

    float acc[4][4] = {};

    for (int k0 = 0; k0 < K; k0 += 16) {
        float4 av, wv;
        if ((EPI & E_MASKA) && !avalid) { av.x=0.f; av.y=0.f; av.z=0.f; av.w=0.f; }
        else av = ld4(Aptr + k0);
        wv = *(const float4*)(Wptr + k0);
        __syncthreads();
        As[lc+0][lr]=av.x; As[lc+1][lr]=av.y; As[lc+2][lr]=av.z; As[lc+3][lr]=av.w;
        Ws[lc+0][lr]=wv.x; Ws[lc+1][lr]=wv.y; Ws[lc+2][lr]=wv.z; Ws[lc+3][lr]=wv.w;
        __syncthreads();
        #pragma unroll
        for (int kk = 0; kk < 16; kk++) {
            const float4 a = *(const float4*)&As[kk][ti<<2];
            const float4 b = *(const float4*)&Ws[kk][tj<<2];
            acc[0][0] += a.x*b.x; acc[0][1] += a.x*b.y; acc[0][2] += a.x*b.z; acc[0][3] += a.x*b.w;
            acc[1][0] += a.y*b.x; acc[1][1] += a.y*b.y; acc[1][2] += a.y*b.z; acc[1][3] += a.y*b.w;
            acc[2][0] += a.z*b.x; acc[2][1] += a.z*b.y; acc[2][2] += a.z*b.z; acc[2][3] += a.z*b.w;
            acc[3][0] += a.w*b.x; acc[3][1] += a.w*b.y; acc[3][2] += a.w*b.z; acc[3][3] += a.w*b.w;
        }
    }

    const int mr = m0 + (ti<<2);
    const int nc = n0 + (tj<<2);
    float4 bv; bv.x=bv.y=bv.z=bv.w=0.f;
    if (EPI & E_BIAS) bv = *(const float4*)(bias + nc);
    #pragma unroll
    for (int r = 0; r < 4; r++) {
        const int m = mr + r;
        float4 v; v.x=acc[r][0]; v.y=acc[r][1]; v.z=acc[r][2]; v.w=acc[r][3];
        if (EPI & E_BIAS) { v.x+=bv.x; v.y+=bv.y; v.z+=bv.z; v.w+=bv.w; }
        if (EPI & E_PE) {
            const float4 p = *(const float4*)(pe + ((size_t)(m & 255) << 8) + nc);
            v.x+=p.x; v.y+=p.y; v.z+=p.z; v.w+=p.w;
        }
        if (EPI & E_RES) {
            const float4 rv = ld4(res + (size_t)m*ldc + nc);
            v.x+=rv.x; v.y+=rv.y; v.z+=rv.z; v.w+=rv.w;
        }
        CT* cp = C + (size_t)m*ldc + nc;
        if (EPI & E_ACC) {
            const float4 cv = ld4((const CT*)cp);
            v.x+=cv.x; v.y+=cv.y; v.z+=cv.z; v.w+=cv.w;
        }
        if (EPI & E_RELU) {
            v.x=fmaxf(v.x,0.f); v.y=fmaxf(v.y,0.f); v.z=fmaxf(v.z,0.f); v.w=fmaxf(v.w,0.f);
        }
        st4(cp, v);
    }
}

// ---------- C = A @ B (no transpose), fp32: r = a @ U_p ----------
__global__ __launch_bounds__(256) void gemm_nn(
    int M, int N, int K,
    const float* __restrict__ A, int lda, int batchA,
    const float* __restrict__ Bm, int ldb, int batchB,
    float* __restrict__ C, int ldc, int batchC)
{
    __shared__ float As[16][68];
    __shared__ float Bs[16][68];
    A  += (size_t)blockIdx.z * batchA;
    Bm += (size_t)blockIdx.z * batchB;
    C  += (size_t)blockIdx.z * batchC;
    const int m0 = blockIdx.y * 64, n0 = blockIdx.x * 64;
    const int tid = threadIdx.x;
    const int lr = tid >> 2;
    const int lc = (tid & 3) << 2;
    const int kr = tid >> 4;
    const int nc4 = (tid & 15) << 2;
    const int ti = tid >> 4;
    const int tj = tid & 15;

    float acc[4][4] = {};

    for (int k0 = 0; k0 < K; k0 += 16) {
        float4 av = *(const float4*)(A + (size_t)(m0 + lr) * lda + k0 + lc);
        float4 bv = *(const float4*)(Bm + (size_t)(k0 + kr) * ldb + n0 + nc4);
        __syncthreads();
        As[lc+0][lr]=av.x; As[lc+1][lr]=av.y; As[lc+2][lr]=av.z; As[lc+3][lr]=av.w;
        *(float4*)&Bs[kr][nc4] = bv;
        __syncthreads();
        #pragma unroll
        for (int kk = 0; kk < 16; kk++) {
            const float4 a = *(const float4*)&As[kk][ti<<2];
            const float4 b = *(const float4*)&Bs[kk][tj<<2];
            acc[0][0] += a.x*b.x; acc[0][1] += a.x*b.y; acc[0][2] += a.x*b.z; acc[0][3] += a.x*b.w;
            acc[1][0] += a.y*b.x; acc[1][1] += a.y*b.y; acc[1][2] += a.y*b.z; acc[1][3] += a.y*b.w;
            acc[2][0] += a.z*b.x; acc[2][1] += a.z*b.y; acc[2][2] += a.z*b.z; acc[2][3] += a.z*b.w;
            acc[3][0] += a.w*b.x; acc[3][1] += a.w*b.y; acc[3][2] += a.w*b.z; acc[3][3] += a.w*b.w;
        }
    }
    const int mr = m0 + (ti<<2);
    const int nc = n0 + (tj<<2);
    #pragma unroll
    for (int r = 0; r < 4; r++) {
        float4 v; v.x=acc[r][0]; v.y=acc[r][1]; v.z=acc[r][2]; v.w=acc[r][3];
        *(float4*)(C + (size_t)(mr + r)*ldc + nc) = v;
    }
}

// ---------- flash attention per (b, head); qkv & o in bf16 ----------
__global__ __launch_bounds__(256) void attn_kernel(const ushort* __restrict__ qkv,
                                                   ushort* __restrict__ o)
{
    __shared__ ushort Kl[256][64];   // 32 KiB
    __shared__ ushort Vl[256][64];   // 32 KiB
    const int b = blockIdx.x, head = blockIdx.y;
    const ushort* base = qkv + (size_t)b * 768 + head * 64;
    for (int idx = threadIdx.x; idx < 256*16; idx += 256) {
        const int row = idx >> 4, c = idx & 15;
        const ushort* rp = base + (size_t)row * (256*768);
        ((uint2*)Kl[row])[c] = ((const uint2*)(rp + 256))[c];
        ((uint2*)Vl[row])[c] = ((const uint2*)(rp + 512))[c];
    }
    __syncthreads();
    const int t = threadIdx.x;
    float q[64];
    const ushort* qrow = base + (size_t)t * (256*768);
    const uint4* q4 = (const uint4*)qrow;
    #pragma unroll
    for (int w = 0; w < 8; w++) {
        const uint4 u = q4[w];
        q[8*w+0] = bf_lo(u.x)*0.125f; q[8*w+1] = bf_hi(u.x)*0.125f;
        q[8*w+2] = bf_lo(u.y)*0.125f; q[8*w+3] = bf_hi(u.y)*0.125f;
        q[8*w+4] = bf_lo(u.z)*0.125f; q[8*w+5] = bf_hi(u.z)*0.125f;
        q[8*w+6] = bf_lo(u.w)*0.125f; q[8*w+7] = bf_hi(u.w)*0.125f;
    }
    float mx = -1e30f, l = 0.f;
    float oa[64];
    #pragma unroll
    for (int d = 0; d < 64; d++) oa[d] = 0.f;
    for (int tp = 0; tp < 256; tp++) {
        const uint2* kr = (const uint2*)(&Kl[tp][0]);
        float s = 0.f;
        #pragma unroll
        for (int w = 0; w < 16; w++) {
            const uint2 u = kr[w];
            s += q[4*w+0] * bf_lo(u.x);
            s += q[4*w+1] * bf_hi(u.x);
            s += q[4*w+2] * bf_lo(u.y);
            s += q[4*w+3] * bf_hi(u.y);
        }
        if (s > mx) {
            const float sc = __expf(mx - s);
            l *= sc;
            #pragma unroll
            for (int d = 0; d < 64; d++) oa[d] *= sc;
            mx = s;
        }
        const float p = __expf(s - mx);
        l += p;
        const uint2* vr = (const uint2*)(&Vl[tp][0]);
        #pragma unroll
        for (int w = 0; w < 16; w++) {
            const uint2 u = vr[w];
            oa[4*w+0] += p * bf_lo(u.x);
            oa[4*w+1] += p * bf_hi(u.x);
            oa[4*w+2] += p * bf_lo(u.y);
            oa[4*w+3] += p * bf_hi(u.y);
        }
    }
    const float inv = 1.f / l;
    ushort* orow = o + (size_t)t * (256*256) + b * 256 + head * 64;
    #pragma unroll
    for (int w = 0; w < 16; w++) {
        ushort4 u;
        u.x = f2bf(oa[4*w+0]*inv); u.y = f2bf(oa[4*w+1]*inv);
        u.z = f2bf(oa[4*w+2]*inv); u.w = f2bf(oa[4*w+3]*inv);
        ((ushort4*)orow)[w] = u;
    }
}

// ---------- LayerNorm over 256 features; one wave per row; optional +addin ----------
template<typename OT>
__global__ __launch_bounds__(256) void ln_kernel(const float* __restrict__ x,
    const float* __restrict__ g, const float* __restrict__ bt,
    const float* __restrict__ addin, OT* __restrict__ out, int nrows)
{
    const int gid = blockIdx.x * 256 + threadIdx.x;
    const int row = gid >> 6;
    const int lane = threadIdx.x & 63;
    if (row >= nrows) return;
    const float* xr = x + (size_t)row * 256;
    float4 v = *(const float4*)(xr + (lane<<2));
    float s = v.x + v.y + v.z + v.w;
    #pragma unroll
    for (int off = 32; off > 0; off >>= 1) s += __shfl_xor(s, off, 64);
    const float mean = s * (1.0f/256.0f);
    const float dx = v.x-mean, dy = v.y-mean, dz = v.z-mean, dw = v.w-mean;
    float ss = dx*dx + dy*dy + dz*dz + dw*dw;
    #pragma unroll
    for (int off = 32; off > 0; off >>= 1) ss += __shfl_xor(ss, off, 64);
    const float inv = rsqrtf(ss * (1.0f/256.0f) + 1e-5f);
    const float4 gv = *(const float4*)(g + (lane<<2));
    const float4 bv = *(const float4*)(bt + (lane<<2));
    float4 ov;
    ov.x = dx*inv*gv.x + bv.x;
    ov.y = dy*inv*gv.y + bv.y;
    ov.z = dz*inv*gv.z + bv.z;
    ov.w = dw*inv*gv.w + bv.w;
    if (addin) {
        const float4 av = *(const float4*)(addin + (size_t)row*256 + (lane<<2));
        ov.x+=av.x; ov.y+=av.y; ov.z+=av.z; ov.w+=av.w;
    }
    st4(out + (size_t)row*256 + (lane<<2), ov);
}

// ---------- masked softmax over i for e[b][t][i], in place, fp32 ----------
__global__ __launch_bounds__(256) void smax_kernel(float* __restrict__ e,
                                                   const int* __restrict__ seqlen)
{
    const int gid = blockIdx.x * 256 + threadIdx.x;
    const int row = gid >> 6;               // row = b*256 + t
    const int lane = threadIdx.x & 63;
    const int L = seqlen[row >> 8];
    float* er = e + (size_t)row * 256;
    float4 v = *(const float4*)(er + (lane<<2));
    const int i0 = lane << 2;
    const float x0 = (i0+0 < L) ? v.x : -1e30f;
    const float x1 = (i0+1 < L) ? v.y : -1e30f;
    const float x2 = (i0+2 < L) ? v.z : -1e30f;
    const float x3 = (i0+3 < L) ? v.w : -1e30f;
    float mx = fmaxf(fmaxf(x0,x1), fmaxf(x2,x3));
    #pragma unroll
    for (int off = 32; off > 0; off >>= 1) mx = fmaxf(mx, __shfl_xor(mx, off, 64));
    const float p0 = (i0+0 < L) ? __expf(x0-mx) : 0.f;
    const float p1 = (i0+1 < L) ? __expf(x1-mx) : 0.f;
    const float p2 = (i0+2 < L) ? __expf(x2-mx) : 0.f;
    const float p3 = (i0+3 < L) ? __expf(x3-mx) : 0.f;
    float s = p0+p1+p2+p3;
    #pragma unroll
    for (int off = 32; off > 0; off >>= 1) s += __shfl_xor(s, off, 64);
    const float inv = 1.f / s;
    v.x = p0*inv; v.y = p1*inv; v.z = p2*inv; v.w = p3*inv;
    *(float4*)(er + (lane<<2)) = v;
}

// ---------- head: logits (512->7) + log_softmax + ragged scatter ----------
__global__ __launch_bounds__(256) void head_kernel(const ushort* __restrict__ hidden,
    const float* __restrict__ Wsm, const float* __restrict__ bsm,
    const int* __restrict__ seqlen, const int* __restrict__ offs,
    float* __restrict__ out)
{
    const int gid = blockIdx.x * 256 + threadIdx.x;
    const int row = gid >> 6;
    const int lane = threadIdx.x & 63;
    if (row >= MTB) return;
    const int t = row >> 8, b = row & 255;
    if (t >= seqlen[b]) return;
    const ushort* hr = hidden + (size_t)row * 512;
    const uint4 hu = *(const uint4*)(hr + lane*8);
    float hv[8];
    hv[0]=bf_lo(hu.x); hv[1]=bf_hi(hu.x); hv[2]=bf_lo(hu.y); hv[3]=bf_hi(hu.y);
    hv[4]=bf_lo(hu.z); hv[5]=bf_hi(hu.z); hv[6]=bf_lo(hu.w); hv[7]=bf_hi(hu.w);
    float lg[7];
    #pragma unroll
    for (int c = 0; c < 7; c++) {
        const float* wr = Wsm + c*512 + lane*8;
        const float4 w0 = *(const float4*)wr;
        const float4 w1 = *(const float4*)(wr + 4);
        float acc = hv[0]*w0.x + hv[1]*w0.y + hv[2]*w0.z + hv[3]*w0.w
                  + hv[4]*w1.x + hv[5]*w1.y + hv[6]*w1.z + hv[7]*w1.w;
        #pragma unroll
        for (int off = 32; off > 0; off >>= 1) acc += __shfl_xor(acc, off, 64);
        lg[c] = acc + bsm[c];
    }
    float mx = lg[0];
    #pragma unroll
    for (int c = 1; c < 7; c++) mx = fmaxf(mx, lg[c]);
    float s = 0.f;
    #pragma unroll
    for (int c = 0; c < 7; c++) s += __expf(lg[c] - mx);
    const float lse = mx + logf(s);
    if (lane == 0) {
        float* orow = out + (size_t)(offs[b] + t) * 7;
        #pragma unroll
        for (int c = 0; c < 7; c++) orow[c] = lg[c] - lse;
    }
}

// ---------- positional encoding over the BATCH dim (faithful quirk) ----------
__global__ void pe_kernel(float* __restrict__ pe)
{
    const int idx = blockIdx.x * 256 + threadIdx.x;   // 65536 = 256x256
    const int b = idx >> 8, f = idx & 255;
    const int j = f >> 1;
    const float div = expf(-9.210340371976184f * (2.0f * j) * (1.0f/256.0f));
    const float arg = (float)b * div;
    pe[idx] = (f & 1) ? cosf(arg) : sinf(arg);
}

// ---------- exclusive prefix sum of seq lengths ----------
__global__ void prefix_kernel(const int* __restrict__ L, int* __restrict__ offs)
{
    if (threadIdx.x == 0) {
        int acc = 0;
        for (int i = 0; i < 256; i++) { offs[i] = acc; acc += L[i]; }
        offs[256] = acc;
    }
}

// ---------- diagnostic: report ws_size via absmax if insufficient ----------
__global__ void sentinel_kernel(float* __restrict__ out, float v)
{
    if (threadIdx.x == 0) out[0] = v;
}

// ---------------------------------------------------------------------------
extern "C" void kernel_launch(void* const* d_in, const int* in_sizes, int n_in,
                              void* d_out, int out_size, void* d_ws, size_t ws_size,
                              hipStream_t stream)
{
    const float* U_s   = (const float*)d_in[0];
    const float* U_p   = (const float*)d_in[1];
    const float* W_emb = (const float*)d_in[2];
    const float* b_emb = (const float*)d_in[3];
    const float* Wqkv  = (const float*)d_in[4];
    const float* bqkv  = (const float*)d_in[5];
    const float* Wo    = (const float*)d_in[6];
    const float* bo    = (const float*)d_in[7];
    const float* ln1_g = (const float*)d_in[8];
    const float* ln1_b = (const float*)d_in[9];
    const float* W1    = (const float*)d_in[10];
    const float* b1    = (const float*)d_in[11];
    const float* W2    = (const float*)d_in[12];
    const float* b2    = (const float*)d_in[13];
    const float* ln2_g = (const float*)d_in[14];
    const float* ln2_b = (const float*)d_in[15];
    const float* W_fc  = (const float*)d_in[16];
    const float* b_fc  = (const float*)d_in[17];
    const float* W_sm  = (const float*)d_in[18];
    const float* b_sm  = (const float*)d_in[19];
    const int*   seqlen= (const int*)d_in[20];
    float* out = (float*)d_out;

    // ---- aliased workspace arena, peak 193 MiB ----
    const size_t MiB = 1024*1024;
    char* ws = (char*)d_ws;
    if (ws_size < 193*MiB) {
        // diagnostic: absmax of output becomes ws_size in MiB
        sentinel_kernel<<<dim3(1), dim3(64), 0, stream>>>(out, -(float)(ws_size / MiB));
        return;
    }
    float*  h    = (float*)(ws);                       // [0,64M)   f32, long-lived
    int*    offs = (int*)  (ws + 64*MiB);              // 4 KiB, survives to end
    float*  pe   = (float*)(ws + 64*MiB + 4096);       // 256 KiB, dead after embed
    ushort* qkv  = (ushort*)(ws + 65*MiB);             // [65,161M) bf16, dead after attn
    ushort* o    = (ushort*)(ws + 161*MiB);            // [161,193M) bf16, dead after res1
    float*  res1 = (float*)(ws + 65*MiB);              // [65,129M) f32 (over dead qkv)
    float*  res2 = res1;
    ushort* h1   = (ushort*)(ws + 161*MiB);            // [161,193M) bf16 (over dead o)
    ushort* ffh  = (ushort*)(ws + 129*MiB);            // [129,161M) bf16
    float*  e    = (float*)(ws + 65*MiB);              // [65,129M) f32 (over dead res2)
    float*  r    = (float*)(ws + 129*MiB);             // [129,193M) f32 (over dead ffh,h1)
    ushort* hid  = (ushort*)(ws + 65*MiB);             // [65,129M) bf16 (over dead e)

    pe_kernel<<<dim3(256), dim3(256), 0, stream>>>(pe);
    prefix_kernel<<<dim3(1), dim3(64), 0, stream>>>(seqlen, offs);

    // h = mask(U_s) @ W_emb^T + b_emb + pe[b,:]
    gemm_nt<E_BIAS|E_PE|E_MASKA, float, float, float><<<dim3(4,1024,1), 256, 0, stream>>>(
        MTB,256,256, U_s,256,0, W_emb,256,0, h,256,0, b_emb, (const float*)nullptr, pe, seqlen);
    // qkv = h @ Wqkv^T + bqkv   (bf16 out)
    gemm_nt<E_BIAS, float, float, ushort><<<dim3(12,1024,1), 256, 0, stream>>>(
        MTB,768,256, h,256,0, Wqkv,256,0, qkv,768,0, bqkv, (const float*)nullptr, nullptr, nullptr);
    // attention -> o  [T,B,256] bf16
    attn_kernel<<<dim3(256,4), 256, 0, stream>>>(qkv, o);
    // res1 = o @ Wo^T + bo + h
    gemm_nt<E_BIAS|E_RES, ushort, float, float><<<dim3(4,1024,1), 256, 0, stream>>>(
        MTB,256,256, o,256,0, Wo,256,0, res1,256,0, bo, h, nullptr, nullptr);
    // h1 = LN1(res1)   (bf16 out)
    ln_kernel<ushort><<<dim3(MTB/4), 256, 0, stream>>>(res1, ln1_g, ln1_b, (const float*)nullptr, h1, MTB);
    // FF in 8 chunks of 256 over DFF
    for (int c = 0; c < 8; c++) {
        gemm_nt<E_BIAS|E_RELU, ushort, float, ushort><<<dim3(4,1024,1), 256, 0, stream>>>(
            MTB,256,256, h1,256,0, W1 + (size_t)c*256*256,256,0, ffh,256,0,
            b1 + c*256, (const float*)nullptr, nullptr, nullptr);
        if (c == 0)
            gemm_nt<E_BIAS|E_RES, ushort, ushort, float><<<dim3(4,1024,1), 256, 0, stream>>>(
                MTB,256,256, ffh,256,0, W2 + c*256,2048,0, res2,256,0,
                b2, h1, nullptr, nullptr);
        else
            gemm_nt<E_ACC, ushort, float, float><<<dim3(4,1024,1), 256, 0, stream>>>(
                MTB,256,256, ffh,256,0, W2 + c*256,2048,0, res2,256,0,
                nullptr, (const float*)nullptr, nullptr, nullptr);
    }
    // q = h + LN2(res2)  (in place into h)
    ln_kernel<float><<<dim3(MTB/4), 256, 0, stream>>>(res2, ln2_g, ln2_b, h, h, MTB);
    // e[b][t][i] = q[t,b,:] . U_p[i,b,:]
    gemm_nt<0, float, float, float><<<dim3(4,4,256), 256, 0, stream>>>(
        256,256,256, h,65536,256, U_p,65536,256, e,256,65536,
        nullptr, (const float*)nullptr, nullptr, nullptr);
    // masked softmax over i
    smax_kernel<<<dim3(MTB/4), 256, 0, stream>>>(e, seqlen);
    // r[t,b,:] = sum_i a[b][t][i] * U_p[i,b,:]
    gemm_nn<<<dim3(4,4,256), 256, 0, stream>>>(
        256,256,256, e,256,65536, U_p,65536,256, r,65536,256);
    // hidden = relu( mask(U_s) @ Wfc[:,:256]^T + r @ Wfc[:,256:]^T + b_fc )  (bf16)
    gemm_nt<E_BIAS|E_MASKA, float, float, ushort><<<dim3(8,1024,1), 256, 0, stream>>>(
        MTB,512,256, U_s,256,0, W_fc,512,0, hid,512,0, b_fc, (const float*)nullptr, nullptr, seqlen);
    gemm_nt<E_ACC|E_RELU, float, float, ushort><<<dim3(8,1024,1), 256, 0, stream>>>(
        MTB,512,256, r,256,0, W_fc + 256,512,0, hid,512,0,
        nullptr, (const float*)nullptr, nullptr, nullptr);
    // logits + log_softmax + ragged gather
    head_kernel<<<dim3(MTB/4), 256, 0, stream>>>(hid, W_sm, b_sm, seqlen, offs, out);
}

// Round 4
// 1799.221 us; speedup vs baseline: 2.2920x; 2.2920x over previous
//
#include <hip/hip_runtime.h>

#define MTB 65536   // T*B rows

typedef unsigned int uint;
typedef unsigned short ushort;

typedef __attribute__((ext_vector_type(8))) short bs8;   // 8 bf16 (4 VGPR)
typedef __attribute__((ext_vector_type(4))) float f4;    // mfma accumulator

// ---------- bf16 helpers ----------
__device__ __forceinline__ ushort f2bf(float x) {
    uint b = __float_as_uint(x);
    b = b + 0x7FFFu + ((b >> 16) & 1u);      // RNE
    return (ushort)(b >> 16);
}
__device__ __forceinline__ float bfu(ushort u) { return __uint_as_float(((uint)u) << 16); }
__device__ __forceinline__ float bf_lo(uint u) { return __uint_as_float(u << 16); }
__device__ __forceinline__ float bf_hi(uint u) { return __uint_as_float(u & 0xFFFF0000u); }

__device__ __forceinline__ float ldsc(const float* p) { return *p; }
__device__ __forceinline__ float ldsc(const ushort* p) { return bfu(*p); }
__device__ __forceinline__ void stsc(float* p, float v) { *p = v; }
__device__ __forceinline__ void stsc(ushort* p, float v) { *p = f2bf(v); }

enum { E_BIAS=1, E_RELU=2, E_ACC=4, E_RES=8, E_PE=16, E_MASKA=32 };

// ---------------------------------------------------------------------------
// Split-precision MFMA GEMM: C = A @ W^T (+epilogue), 128x128 tile, BK=32.
// A: [M,K] (f32 -> hi/lo split, AMODE=0) or bf16-exact (AMODE=1).
// W: f32, [N,K] row-major (BTR=0) or [K,N] row-major (BTR=1, transposed stage).
// Always split W into hi+lo. MFMA: Ahi*Bhi + Ahi*Blo (+ Alo*Bhi if AMODE=0).
// 4 waves = 2x2, each computes 64x64 via 4x4 frags of 16x16x32 bf16 MFMA.
// ---------------------------------------------------------------------------
template<int EPI, int AMODE, int BTR, typename AT, typename CT, typename RT>
__global__ __launch_bounds__(256) void gemm_mfma(
    int M, int N, int K,
    const AT* __restrict__ A, int lda, long batchA,
    const float* __restrict__ W, int ldw, long batchW,
    CT* __restrict__ C, int ldc, long batchC,
    const float* __restrict__ bias,
    const RT* __restrict__ res,
    const float* __restrict__ pe,
    const int* __restrict__ seqlen)
{
    __shared__ ushort Ahi[128][40];
    __shared__ ushort Alo[128][40];
    __shared__ ushort Bhi[128][40];
    __shared__ ushort Blo[128][40];
    A += (size_t)blockIdx.z * batchA;
    W += (size_t)blockIdx.z * batchW;
    C += (size_t)blockIdx.z * batchC;
    const int m0 = blockIdx.y * 128, n0 = blockIdx.x * 128;
    const int tid = threadIdx.x;
    const int lane = tid & 63, wid = tid >> 6;
    const int wr = wid >> 1, wc = wid & 1;

    f4 acc[4][4];
    {
        f4 z = {0.f, 0.f, 0.f, 0.f};
        #pragma unroll
        for (int i = 0; i < 4; i++)
            #pragma unroll
            for (int j = 0; j < 4; j++) acc[i][j] = z;
    }

    for (int k0 = 0; k0 < K; k0 += 32) {
        __syncthreads();
        // ---- stage A ----
        if (AMODE == 0) {
            const float* Af = (const float*)A;
            #pragma unroll
            for (int i = 0; i < 4; i++) {
                const int row = i*32 + (tid>>3);
                const int cg  = (tid&7)<<2;
                const int m = m0 + row;
                float4 v; v.x=0.f; v.y=0.f; v.z=0.f; v.w=0.f;
                bool ok = true;
                if (EPI & E_MASKA) ok = ((m>>8) < seqlen[m&255]);
                if (ok) v = *(const float4*)(Af + (size_t)m*lda + k0 + cg);
                ushort4 h4, l4;
                h4.x=f2bf(v.x); l4.x=f2bf(v.x - bfu(h4.x));
                h4.y=f2bf(v.y); l4.y=f2bf(v.y - bfu(h4.y));
                h4.z=f2bf(v.z); l4.z=f2bf(v.z - bfu(h4.z));
                h4.w=f2bf(v.w); l4.w=f2bf(v.w - bfu(h4.w));
                *(ushort4*)&Ahi[row][cg] = h4;
                *(ushort4*)&Alo[row][cg] = l4;
            }
        } else {
            const ushort* Ab = (const ushort*)A;
            #pragma unroll
            for (int i = 0; i < 2; i++) {
                const int row = i*64 + (tid>>2);
                const int cg  = (tid&3)<<3;
                *(uint4*)&Ahi[row][cg] =
                    *(const uint4*)(Ab + (size_t)(m0+row)*lda + k0 + cg);
            }
        }
        // ---- stage B (from f32 W) ----
        if (BTR == 0) {
            #pragma unroll
            for (int i = 0; i < 4; i++) {
                const int row = i*32 + (tid>>3);
                const int cg  = (tid&7)<<2;
                float4 v = *(const float4*)(W + (size_t)(n0+row)*ldw + k0 + cg);
                ushort4 h4, l4;
                h4.x=f2bf(v.x); l4.x=f2bf(v.x - bfu(h4.x));
                h4.y=f2bf(v.y); l4.y=f2bf(v.y - bfu(h4.y));
                h4.z=f2bf(v.z); l4.z=f2bf(v.z - bfu(h4.z));
                h4.w=f2bf(v.w); l4.w=f2bf(v.w - bfu(h4.w));
                *(ushort4*)&Bhi[row][cg] = h4;
                *(ushort4*)&Blo[row][cg] = l4;
            }
        } else {
            #pragma unroll
            for (int i = 0; i < 4; i++) {
                const int kr = i*8 + (tid>>5);
                const int ng = (tid&31)<<2;
                float4 v = *(const float4*)(W + (size_t)(k0+kr)*ldw + n0 + ng);
                float xs[4] = {v.x, v.y, v.z, v.w};
                #pragma unroll
                for (int j = 0; j < 4; j++) {
                    ushort hh = f2bf(xs[j]);
                    Bhi[ng+j][kr] = hh;
                    Blo[ng+j][kr] = f2bf(xs[j] - bfu(hh));
                }
            }
        }
        __syncthreads();
        // ---- fragments + MFMA ----
        const int lr = lane & 15, lk = (lane>>4)<<3;
        bs8 ah[4], bh[4], bl[4];
        #pragma unroll
        for (int i = 0; i < 4; i++) {
            ah[i] = *(const bs8*)&Ahi[wr*64 + i*16 + lr][lk];
            bh[i] = *(const bs8*)&Bhi[wc*64 + i*16 + lr][lk];
            bl[i] = *(const bs8*)&Blo[wc*64 + i*16 + lr][lk];
        }
        #pragma unroll
        for (int mi = 0; mi < 4; mi++)
            #pragma unroll
            for (int ni = 0; ni < 4; ni++) {
                acc[mi][ni] = __builtin_amdgcn_mfma_f32_16x16x32_bf16(ah[mi], bh[ni], acc[mi][ni], 0, 0, 0);
                acc[mi][ni] = __builtin_amdgcn_mfma_f32_16x16x32_bf16(ah[mi], bl[ni], acc[mi][ni], 0, 0, 0);
            }
        if (AMODE == 0) {
            bs8 al[4];
            #pragma unroll
            for (int i = 0; i < 4; i++)
                al[i] = *(const bs8*)&Alo[wr*64 + i*16 + lr][lk];
            #pragma unroll
            for (int mi = 0; mi < 4; mi++)
                #pragma unroll
                for (int ni = 0; ni < 4; ni++)
                    acc[mi][ni] = __builtin_amdgcn_mfma_f32_16x16x32_bf16(al[mi], bh[ni], acc[mi][ni], 0, 0, 0);
        }
    }
    // ---- epilogue: C row = (lane>>4)*4+reg, col = lane&15 ----
    const int colb = n0 + wc*64;
    const int rowb = m0 + wr*64;
    #pragma unroll
    for (int ni = 0; ni < 4; ni++) {
        const int col = colb + ni*16 + (lane & 15);
        float bv = (EPI & E_BIAS) ? bias[col] : 0.f;
        #pragma unroll
        for (int mi = 0; mi < 4; mi++) {
            const int r0 = rowb + mi*16 + ((lane>>4)<<2);
            #pragma unroll
            for (int j = 0; j < 4; j++) {
                const int row = r0 + j;
                float v = acc[mi][ni][j] + bv;
                if (EPI & E_PE)  v += pe[((row & 255) << 8) + col];
                if (EPI & E_RES) v += ldsc(res + (size_t)row*ldc + col);
                CT* cp = C + (size_t)row*ldc + col;
                if (EPI & E_ACC) v += ldsc((const CT*)cp);
                if (EPI & E_RELU) v = fmaxf(v, 0.f);
                stsc(cp, v);
            }
        }
    }
}

// ---------- flash attention per (b, head); K/V unpacked to f32 LDS ----------
__global__ __launch_bounds__(256) void attn_kernel(const ushort* __restrict__ qkv,
                                                   ushort* __restrict__ o)
{
    __shared__ float Kf[128][68];   // 34.8 KB
    __shared__ float Vf[128][68];
    const int b = blockIdx.x, head = blockIdx.y;
    const ushort* base = qkv + (size_t)b * 768 + head * 64;
    const int t = threadIdx.x;
    float q[64];
    {
        const uint4* q4 = (const uint4*)(base + (size_t)t * 196608);
        #pragma unroll
        for (int w = 0; w < 8; w++) {
            const uint4 u = q4[w];
            q[8*w+0] = bf_lo(u.x)*0.125f; q[8*w+1] = bf_hi(u.x)*0.125f;
            q[8*w+2] = bf_lo(u.y)*0.125f; q[8*w+3] = bf_hi(u.y)*0.125f;
            q[8*w+4] = bf_lo(u.z)*0.125f; q[8*w+5] = bf_hi(u.z)*0.125f;
            q[8*w+6] = bf_lo(u.w)*0.125f; q[8*w+7] = bf_hi(u.w)*0.125f;
        }
    }
    float mx = -1e30f, l = 0.f;
    float oa[64];
    #pragma unroll
    for (int d = 0; d < 64; d++) oa[d] = 0.f;

    for (int kt = 0; kt < 2; kt++) {
        __syncthreads();
        #pragma unroll
        for (int i = 0; i < 4; i++) {
            const int id = i*256 + t;
            const int row = id >> 3, c8 = (id & 7) << 3;
            const ushort* rp = base + (size_t)(kt*128 + row) * 196608;
            uint4 uk = *(const uint4*)(rp + 256 + c8);
            uint4 uv = *(const uint4*)(rp + 512 + c8);
            float* kd = &Kf[row][c8];
            float* vd = &Vf[row][c8];
            kd[0]=bf_lo(uk.x); kd[1]=bf_hi(uk.x); kd[2]=bf_lo(uk.y); kd[3]=bf_hi(uk.y);
            kd[4]=bf_lo(uk.z); kd[5]=bf_hi(uk.z); kd[6]=bf_lo(uk.w); kd[7]=bf_hi(uk.w);
            vd[0]=bf_lo(uv.x); vd[1]=bf_hi(uv.x); vd[2]=bf_lo(uv.y); vd[3]=bf_hi(uv.y);
            vd[4]=bf_lo(uv.z); vd[5]=bf_hi(uv.z); vd[6]=bf_lo(uv.w); vd[7]=bf_hi(uv.w);
        }
        __syncthreads();
        for (int tp = 0; tp < 128; tp++) {
            const float* kr = &Kf[tp][0];
            float s = 0.f;
            #pragma unroll
            for (int d = 0; d < 64; d++) s += q[d] * kr[d];
            if (s > mx) {
                const float sc = __expf(mx - s);
                l *= sc;
                #pragma unroll
                for (int d = 0; d < 64; d++) oa[d] *= sc;
                mx = s;
            }
            const float p = __expf(s - mx);
            l += p;
            const float* vr = &Vf[tp][0];
            #pragma unroll
            for (int d = 0; d < 64; d++) oa[d] += p * vr[d];
        }
    }
    const float inv = 1.f / l;
    ushort* orow = o + (size_t)t * 65536 + b * 256 + head * 64;
    #pragma unroll
    for (int w = 0; w < 16; w++) {
        ushort4 u;
        u.x = f2bf(oa[4*w+0]*inv); u.y = f2bf(oa[4*w+1]*inv);
        u.z = f2bf(oa[4*w+2]*inv); u.w = f2bf(oa[4*w+3]*inv);
        ((ushort4*)orow)[w] = u;
    }
}

// ---------- LayerNorm over 256 features; one wave per row; optional +addin ----------
template<typename OT>
__global__ __launch_bounds__(256) void ln_kernel(const float* __restrict__ x,
    const float* __restrict__ g, const float* __restrict__ bt,
    const float* __restrict__ addin, OT* __restrict__ out, int nrows)
{
    const int gid = blockIdx.x * 256 + threadIdx.x;
    const int row = gid >> 6;
    const int lane = threadIdx.x & 63;
    if (row >= nrows) return;
    const float* xr = x + (size_t)row * 256;
    float4 v = *(const float4*)(xr + (lane<<2));
    float s = v.x + v.y + v.z + v.w;
    #pragma unroll
    for (int off = 32; off > 0; off >>= 1) s += __shfl_xor(s, off, 64);
    const float mean = s * (1.0f/256.0f);
    const float dx = v.x-mean, dy = v.y-mean, dz = v.z-mean, dw = v.w-mean;
    float ss = dx*dx + dy*dy + dz*dz + dw*dw;
    #pragma unroll
    for (int off = 32; off > 0; off >>= 1) ss += __shfl_xor(ss, off, 64);
    const float inv = rsqrtf(ss * (1.0f/256.0f) + 1e-5f);
    const float4 gv = *(const float4*)(g + (lane<<2));
    const float4 bv = *(const float4*)(bt + (lane<<2));
    float4 ov;
    ov.x = dx*inv*gv.x + bv.x;
    ov.y = dy*inv*gv.y + bv.y;
    ov.z = dz*inv*gv.z + bv.z;
    ov.w = dw*inv*gv.w + bv.w;
    if (addin) {
        const float4 av = *(const float4*)(addin + (size_t)row*256 + (lane<<2));
        ov.x+=av.x; ov.y+=av.y; ov.z+=av.z; ov.w+=av.w;
    }
    OT* op = out + (size_t)row*256 + (lane<<2);
    stsc(op+0, ov.x); stsc(op+1, ov.y); stsc(op+2, ov.z); stsc(op+3, ov.w);
}

// ---------- masked softmax over i for e[b][t][i], in place, fp32 ----------
__global__ __launch_bounds__(256) void smax_kernel(float* __restrict__ e,
                                                   const int* __restrict__ seqlen)
{
    const int gid = blockIdx.x * 256 + threadIdx.x;
    const int row = gid >> 6;               // row = b*256 + t
    const int lane = threadIdx.x & 63;
    const int L = seqlen[row >> 8];
    float* er = e + (size_t)row * 256;
    float4 v = *(const float4*)(er + (lane<<2));
    const int i0 = lane << 2;
    const float x0 = (i0+0 < L) ? v.x : -1e30f;
    const float x1 = (i0+1 < L) ? v.y : -1e30f;
    const float x2 = (i0+2 < L) ? v.z : -1e30f;
    const float x3 = (i0+3 < L) ? v.w : -1e30f;
    float mx = fmaxf(fmaxf(x0,x1), fmaxf(x2,x3));
    #pragma unroll
    for (int off = 32; off > 0; off >>= 1) mx = fmaxf(mx, __shfl_xor(mx, off, 64));
    const float p0 = (i0+0 < L) ? __expf(x0-mx) : 0.f;
    const float p1 = (i0+1 < L) ? __expf(x1-mx) : 0.f;
    const float p2 = (i0+2 < L) ? __expf(x2-mx) : 0.f;
    const float p3 = (i0+3 < L) ? __expf(x3-mx) : 0.f;
    float s = p0+p1+p2+p3;
    #pragma unroll
    for (int off = 32; off > 0; off >>= 1) s += __shfl_xor(s, off, 64);
    const float inv = 1.f / s;
    v.x = p0*inv; v.y = p1*inv; v.z = p2*inv; v.w = p3*inv;
    *(float4*)(er + (lane<<2)) = v;
}

// ---------- head: logits (512->7) + log_softmax + ragged scatter; hid bf16 ----------
__global__ __launch_bounds__(256) void head_kernel(const ushort* __restrict__ hidden,
    const float* __restrict__ Wsm, const float* __restrict__ bsm,
    const int* __restrict__ seqlen, const int* __restrict__ offs,
    float* __restrict__ out)
{
    const int gid = blockIdx.x * 256 + threadIdx.x;
    const int row = gid >> 6;
    const int lane = threadIdx.x & 63;
    if (row >= MTB) return;
    const int t = row >> 8, b = row & 255;
    if (t >= seqlen[b]) return;
    const ushort* hr = hidden + (size_t)row * 512;
    const uint4 hu = *(const uint4*)(hr + lane*8);
    float hv[8];
    hv[0]=bf_lo(hu.x); hv[1]=bf_hi(hu.x); hv[2]=bf_lo(hu.y); hv[3]=bf_hi(hu.y);
    hv[4]=bf_lo(hu.z); hv[5]=bf_hi(hu.z); hv[6]=bf_lo(hu.w); hv[7]=bf_hi(hu.w);
    float lg[7];
    #pragma unroll
    for (int c = 0; c < 7; c++) {
        const float* wr = Wsm + c*512 + lane*8;
        const float4 w0 = *(const float4*)wr;
        const float4 w1 = *(const float4*)(wr + 4);
        float acc = hv[0]*w0.x + hv[1]*w0.y + hv[2]*w0.z + hv[3]*w0.w
                  + hv[4]*w1.x + hv[5]*w1.y + hv[6]*w1.z + hv[7]*w1.w;
        #pragma unroll
        for (int off = 32; off > 0; off >>= 1) acc += __shfl_xor(acc, off, 64);
        lg[c] = acc + bsm[c];
    }
    float mx = lg[0];
    #pragma unroll
    for (int c = 1; c < 7; c++) mx = fmaxf(mx, lg[c]);
    float s = 0.f;
    #pragma unroll
    for (int c = 0; c < 7; c++) s += __expf(lg[c] - mx);
    const float lse = mx + logf(s);
    if (lane == 0) {
        float* orow = out + (size_t)(offs[b] + t) * 7;
        #pragma unroll
        for (int c = 0; c < 7; c++) orow[c] = lg[c] - lse;
    }
}

// ---------- positional encoding over the BATCH dim (faithful quirk) ----------
__global__ void pe_kernel(float* __restrict__ pe)
{
    const int idx = blockIdx.x * 256 + threadIdx.x;   // 65536 = 256x256
    const int b = idx >> 8, f = idx & 255;
    const int j = f >> 1;
    const float div = expf(-9.210340371976184f * (2.0f * j) * (1.0f/256.0f));
    const float arg = (float)b * div;
    pe[idx] = (f & 1) ? cosf(arg) : sinf(arg);
}

// ---------- exclusive prefix sum of seq lengths ----------
__global__ void prefix_kernel(const int* __restrict__ L, int* __restrict__ offs)
{
    if (threadIdx.x == 0) {
        int acc = 0;
        for (int i = 0; i < 256; i++) { offs[i] = acc; acc += L[i]; }
        offs[256] = acc;
    }
}

// ---------- diagnostic: report ws_size via absmax if insufficient ----------
__global__ void sentinel_kernel(float* __restrict__ out, float v)
{
    if (threadIdx.x == 0) out[0] = v;
}

// ---------------------------------------------------------------------------
extern "C" void kernel_launch(void* const* d_in, const int* in_sizes, int n_in,
                              void* d_out, int out_size, void* d_ws, size_t ws_size,
                              hipStream_t stream)
{
    const float* U_s   = (const float*)d_in[0];
    const float* U_p   = (const float*)d_in[1];
    const float* W_emb = (const float*)d_in[2];
    const float* b_emb = (const float*)d_in[3];
    const float* Wqkv  = (const float*)d_in[4];
    const float* bqkv  = (const float*)d_in[5];
    const float* Wo    = (const float*)d_in[6];
    const float* bo    = (const float*)d_in[7];
    const float* ln1_g = (const float*)d_in[8];
    const float* ln1_b = (const float*)d_in[9];
    const float* W1    = (const float*)d_in[10];
    const float* b1    = (const float*)d_in[11];
    const float* W2    = (const float*)d_in[12];
    const float* b2    = (const float*)d_in[13];
    const float* ln2_g = (const float*)d_in[14];
    const float* ln2_b = (const float*)d_in[15];
    const float* W_fc  = (const float*)d_in[16];
    const float* b_fc  = (const float*)d_in[17];
    const float* W_sm  = (const float*)d_in[18];
    const float* b_sm  = (const float*)d_in[19];
    const int*   seqlen= (const int*)d_in[20];
    float* out = (float*)d_out;

    // ---- aliased workspace arena, peak 193 MiB (known-good from round 2) ----
    const size_t MiB = 1024*1024;
    char* ws = (char*)d_ws;
    if (ws_size < 193*MiB) {
        sentinel_kernel<<<dim3(1), dim3(64), 0, stream>>>(out, -(float)(ws_size / MiB));
        return;
    }
    float*  h    = (float*)(ws);                       // [0,64M)   f32, long-lived
    int*    offs = (int*)  (ws + 64*MiB);              // 4 KiB
    float*  pe   = (float*)(ws + 64*MiB + 4096);       // 256 KiB, dead after embed
    ushort* qkv  = (ushort*)(ws + 65*MiB);             // [65,161M)  bf16, dead after attn
    ushort* o    = (ushort*)(ws + 161*MiB);            // [161,193M) bf16, dead after proj
    float*  res1 = (float*)(ws + 65*MiB);              // [65,129M)  f32 (over dead qkv)
    float*  res2 = res1;
    ushort* h1   = (ushort*)(ws + 161*MiB);            // [161,193M) bf16 (over dead o)
    ushort* ffh  = (ushort*)(ws + 129*MiB);            // [129,161M) bf16
    float*  e    = (float*)(ws + 65*MiB);              // [65,129M)  f32 (over dead res2)
    float*  r    = (float*)(ws + 129*MiB);             // [129,193M) f32 (over dead ffh,h1)
    ushort* hid  = (ushort*)(ws + 65*MiB);             // [65,129M)  bf16 (over dead e) — 64 MiB exactly

    pe_kernel<<<dim3(256), dim3(256), 0, stream>>>(pe);
    prefix_kernel<<<dim3(1), dim3(64), 0, stream>>>(seqlen, offs);

    // h = mask(U_s) @ W_emb^T + b_emb + pe[b,:]
    gemm_mfma<E_BIAS|E_PE|E_MASKA, 0, 0, float, float, float>
        <<<dim3(2,512,1), 256, 0, stream>>>(
        MTB,256,256, U_s,256,0, W_emb,256,0, h,256,0, b_emb, (const float*)nullptr, pe, seqlen);
    // qkv = h @ Wqkv^T + bqkv   (bf16 out)
    gemm_mfma<E_BIAS, 0, 0, float, ushort, float>
        <<<dim3(6,512,1), 256, 0, stream>>>(
        MTB,768,256, h,256,0, Wqkv,256,0, qkv,768,0, bqkv, (const float*)nullptr, nullptr, nullptr);
    // attention -> o  [T,B,256] bf16
    attn_kernel<<<dim3(256,4), 256, 0, stream>>>(qkv, o);
    // res1 = o @ Wo^T + bo + h
    gemm_mfma<E_BIAS|E_RES, 1, 0, ushort, float, float>
        <<<dim3(2,512,1), 256, 0, stream>>>(
        MTB,256,256, o,256,0, Wo,256,0, res1,256,0, bo, h, nullptr, nullptr);
    // h1 = LN1(res1)   (bf16 out)
    ln_kernel<ushort><<<dim3(MTB/4), 256, 0, stream>>>(res1, ln1_g, ln1_b, (const float*)nullptr, h1, MTB);
    // FF in 8 chunks of 256 over DFF=2048
    for (int c = 0; c < 8; c++) {
        gemm_mfma<E_BIAS|E_RELU, 1, 0, ushort, ushort, float>
            <<<dim3(2,512,1), 256, 0, stream>>>(
            MTB,256,256, h1,256,0, W1 + (size_t)c*256*256,256,0, ffh,256,0,
            b1 + c*256, (const float*)nullptr, nullptr, nullptr);
        if (c == 0)
            gemm_mfma<E_BIAS|E_RES, 1, 0, ushort, float, ushort>
                <<<dim3(2,512,1), 256, 0, stream>>>(
                MTB,256,256, ffh,256,0, W2 + c*256,2048,0, res2,256,0,
                b2, h1, nullptr, nullptr);
        else
            gemm_mfma<E_ACC, 1, 0, ushort, float, float>
                <<<dim3(2,512,1), 256, 0, stream>>>(
                MTB,256,256, ffh,256,0, W2 + c*256,2048,0, res2,256,0,
                nullptr, (const float*)nullptr, nullptr, nullptr);
    }
    // q = h + LN2(res2)  (in place into h)
    ln_kernel<float><<<dim3(MTB/4), 256, 0, stream>>>(res2, ln2_g, ln2_b, h, h, MTB);
    // e[b][t][i] = q[t,b,:] . U_p[i,b,:]
    gemm_mfma<0, 0, 0, float, float, float>
        <<<dim3(2,2,256), 256, 0, stream>>>(
        256,256,256, h,65536,256, U_p,65536,256, e,256,65536,
        nullptr, (const float*)nullptr, nullptr, nullptr);
    // masked softmax over i
    smax_kernel<<<dim3(MTB/4), 256, 0, stream>>>(e, seqlen);
    // r[t,b,:] = sum_i a[b][t][i] * U_p[i,b,:]   (B non-transposed -> BTR=1)
    gemm_mfma<0, 0, 1, float, float, float>
        <<<dim3(2,2,256), 256, 0, stream>>>(
        256,256,256, e,256,65536, U_p,65536,256, r,65536,256,
        nullptr, (const float*)nullptr, nullptr, nullptr);
    // hidden = relu( mask(U_s) @ Wfc[:,:256]^T + r @ Wfc[:,256:]^T + b_fc )  (bf16)
    gemm_mfma<E_BIAS|E_MASKA, 0, 0, float, ushort, float>
        <<<dim3(4,512,1), 256, 0, stream>>>(
        MTB,512,256, U_s,256,0, W_fc,512,0, hid,512,0, b_fc, (const float*)nullptr, nullptr, seqlen);
    gemm_mfma<E_ACC|E_RELU, 0, 0, float, ushort, float>
        <<<dim3(4,512,1), 256, 0, stream>>>(
        MTB,512,256, r,256,0, W_fc + 256,512,0, hid,512,0,
        nullptr, (const float*)nullptr, nullptr, nullptr);
    // logits + log_softmax + ragged gather
    head_kernel<<<dim3(MTB/4), 256, 0, stream>>>(hid, W_sm, b_sm, seqlen, offs, out);
}

// Round 6
// 1716.485 us; speedup vs baseline: 2.4024x; 1.0482x over previous
//
#include <hip/hip_runtime.h>

#define MTB 65536   // T*B rows

typedef unsigned int uint;
typedef unsigned short ushort;

typedef __attribute__((ext_vector_type(8))) short bs8;   // 8 bf16 (4 VGPR)
typedef __attribute__((ext_vector_type(4))) float f4;    // mfma accumulator

// ---------- bf16 helpers ----------
__device__ __forceinline__ ushort f2bf(float x) {
    uint b = __float_as_uint(x);
    b = b + 0x7FFFu + ((b >> 16) & 1u);      // RNE
    return (ushort)(b >> 16);
}
__device__ __forceinline__ float bfu(ushort u) { return __uint_as_float(((uint)u) << 16); }
__device__ __forceinline__ float bf_lo(uint u) { return __uint_as_float(u << 16); }
__device__ __forceinline__ float bf_hi(uint u) { return __uint_as_float(u & 0xFFFF0000u); }

__device__ __forceinline__ float ldsc(const float* p) { return *p; }
__device__ __forceinline__ float ldsc(const ushort* p) { return bfu(*p); }
__device__ __forceinline__ void stsc(float* p, float v) { *p = v; }
__device__ __forceinline__ void stsc(ushort* p, float v) { *p = f2bf(v); }

enum { E_BIAS=1, E_RELU=2, E_ACC=4, E_RES=8, E_PE=16, E_MASKA=32 };

// ---------------------------------------------------------------------------
// Split-precision MFMA GEMM: C = A @ W^T (+epilogue), 128x128 tile, BK=32.
// AMODE: 0 = A f32 -> split hi/lo in staging;  1 = A bf16 exact (hi only).
// BMODE: 0 = W f32 [N,K] nt, split in staging
//        1 = W f32 [K,N] nn, split+transpose in staging
//        2 = W pre-split bf16 planes (Whi,Wlo) [N,K], copy staging
// MFMA terms: Ahi*Bhi + Ahi*Blo (+ Alo*Bhi if AMODE==0).
// 4 waves = 2x2, each 64x64 out via 4x4 frags of 16x16x32 bf16 MFMA.
// ---------------------------------------------------------------------------
template<int EPI, int AMODE, int BMODE, typename AT, typename CT, typename RT>
__global__ __launch_bounds__(256) void gemm_mfma(
    int M, int N, int K,
    const AT* __restrict__ A, int lda, long batchA,
    const void* __restrict__ Wp, const void* __restrict__ Wp2, int ldw, long batchW,
    CT* __restrict__ C, int ldc, long batchC,
    const float* __restrict__ bias,
    const RT* __restrict__ res,
    const float* __restrict__ pe,
    const int* __restrict__ seqlen)
{
    __shared__ ushort Ahi[128][40];
    __shared__ ushort Alo[128][40];
    __shared__ ushort Bhi[128][40];
    __shared__ ushort Blo[128][40];
    A += (size_t)blockIdx.z * batchA;
    C += (size_t)blockIdx.z * batchC;
    const float* Wf = (const float*)Wp + (size_t)blockIdx.z * batchW;   // modes 0/1
    const ushort* Wh = (const ushort*)Wp;                                // mode 2
    const ushort* Wl = (const ushort*)Wp2;
    const int m0 = blockIdx.y * 128, n0 = blockIdx.x * 128;
    const int tid = threadIdx.x;
    const int lane = tid & 63, wid = tid >> 6;
    const int wr = wid >> 1, wc = wid & 1;

    f4 acc[4][4];
    {
        f4 z = {0.f, 0.f, 0.f, 0.f};
        #pragma unroll
        for (int i = 0; i < 4; i++)
            #pragma unroll
            for (int j = 0; j < 4; j++) acc[i][j] = z;
    }

    for (int k0 = 0; k0 < K; k0 += 32) {
        __syncthreads();
        // ---- stage A ----
        if (AMODE == 0) {
            const float* Af = (const float*)A;
            #pragma unroll
            for (int i = 0; i < 4; i++) {
                const int row = i*32 + (tid>>3);
                const int cg  = (tid&7)<<2;
                const int m = m0 + row;
                float4 v; v.x=0.f; v.y=0.f; v.z=0.f; v.w=0.f;
                bool ok = true;
                if (EPI & E_MASKA) ok = ((m>>8) < seqlen[m&255]);
                if (ok) v = *(const float4*)(Af + (size_t)m*lda + k0 + cg);
                ushort4 h4, l4;
                h4.x=f2bf(v.x); l4.x=f2bf(v.x - bfu(h4.x));
                h4.y=f2bf(v.y); l4.y=f2bf(v.y - bfu(h4.y));
                h4.z=f2bf(v.z); l4.z=f2bf(v.z - bfu(h4.z));
                h4.w=f2bf(v.w); l4.w=f2bf(v.w - bfu(h4.w));
                *(ushort4*)&Ahi[row][cg] = h4;
                *(ushort4*)&Alo[row][cg] = l4;
            }
        } else {
            const ushort* Ab = (const ushort*)A;
            #pragma unroll
            for (int i = 0; i < 2; i++) {
                const int row = i*64 + (tid>>2);
                const int cg  = (tid&3)<<3;
                *(uint4*)&Ahi[row][cg] =
                    *(const uint4*)(Ab + (size_t)(m0+row)*lda + k0 + cg);
            }
        }
        // ---- stage B ----
        if (BMODE == 2) {
            // 128 rows x 32 cols per plane; 256 threads x 16 ushorts (2x uint4)
            const int row = tid >> 1;            // 0..127
            const int hk  = (tid & 1) << 4;      // 0 or 16
            const size_t off = (size_t)(n0 + row) * ldw + k0 + hk;
            *(uint4*)&Bhi[row][hk]     = *(const uint4*)(Wh + off);
            *(uint4*)&Bhi[row][hk + 8] = *(const uint4*)(Wh + off + 8);
            *(uint4*)&Blo[row][hk]     = *(const uint4*)(Wl + off);
            *(uint4*)&Blo[row][hk + 8] = *(const uint4*)(Wl + off + 8);
        } else if (BMODE == 0) {
            #pragma unroll
            for (int i = 0; i < 4; i++) {
                const int row = i*32 + (tid>>3);
                const int cg  = (tid&7)<<2;
                float4 v = *(const float4*)(Wf + (size_t)(n0+row)*ldw + k0 + cg);
                ushort4 h4, l4;
                h4.x=f2bf(v.x); l4.x=f2bf(v.x - bfu(h4.x));
                h4.y=f2bf(v.y); l4.y=f2bf(v.y - bfu(h4.y));
                h4.z=f2bf(v.z); l4.z=f2bf(v.z - bfu(h4.z));
                h4.w=f2bf(v.w); l4.w=f2bf(v.w - bfu(h4.w));
                *(ushort4*)&Bhi[row][cg] = h4;
                *(ushort4*)&Blo[row][cg] = l4;
            }
        } else {  // BMODE == 1 : W[k][n], transpose while staging
            #pragma unroll
            for (int i = 0; i < 4; i++) {
                const int kr = i*8 + (tid>>5);
                const int ng = (tid&31)<<2;
                float4 v = *(const float4*)(Wf + (size_t)(k0+kr)*ldw + n0 + ng);
                float xs[4] = {v.x, v.y, v.z, v.w};
                #pragma unroll
                for (int j = 0; j < 4; j++) {
                    ushort hh = f2bf(xs[j]);
                    Bhi[ng+j][kr] = hh;
                    Blo[ng+j][kr] = f2bf(xs[j] - bfu(hh));
                }
            }
        }
        __syncthreads();
        // ---- fragments + MFMA ----
        const int lr = lane & 15, lk = (lane>>4)<<3;
        bs8 ah[4], bh[4], bl[4];
        #pragma unroll
        for (int i = 0; i < 4; i++) {
            ah[i] = *(const bs8*)&Ahi[wr*64 + i*16 + lr][lk];
            bh[i] = *(const bs8*)&Bhi[wc*64 + i*16 + lr][lk];
            bl[i] = *(const bs8*)&Blo[wc*64 + i*16 + lr][lk];
        }
        #pragma unroll
        for (int mi = 0; mi < 4; mi++)
            #pragma unroll
            for (int ni = 0; ni < 4; ni++) {
                acc[mi][ni] = __builtin_amdgcn_mfma_f32_16x16x32_bf16(ah[mi], bh[ni], acc[mi][ni], 0, 0, 0);
                acc[mi][ni] = __builtin_amdgcn_mfma_f32_16x16x32_bf16(ah[mi], bl[ni], acc[mi][ni], 0, 0, 0);
            }
        if (AMODE == 0) {
            bs8 al[4];
            #pragma unroll
            for (int i = 0; i < 4; i++)
                al[i] = *(const bs8*)&Alo[wr*64 + i*16 + lr][lk];
            #pragma unroll
            for (int mi = 0; mi < 4; mi++)
                #pragma unroll
                for (int ni = 0; ni < 4; ni++)
                    acc[mi][ni] = __builtin_amdgcn_mfma_f32_16x16x32_bf16(al[mi], bh[ni], acc[mi][ni], 0, 0, 0);
        }
    }
    // ---- epilogue: C row = 4*(lane>>4)+reg, col = lane&15 ----
    const int colb = n0 + wc*64;
    const int rowb = m0 + wr*64;
    #pragma unroll
    for (int ni = 0; ni < 4; ni++) {
        const int col = colb + ni*16 + (lane & 15);
        float bv = (EPI & E_BIAS) ? bias[col] : 0.f;
        #pragma unroll
        for (int mi = 0; mi < 4; mi++) {
            const int r0 = rowb + mi*16 + ((lane>>4)<<2);
            #pragma unroll
            for (int j = 0; j < 4; j++) {
                const int row = r0 + j;
                float v = acc[mi][ni][j] + bv;
                if (EPI & E_PE)  v += pe[((row & 255) << 8) + col];
                if (EPI & E_RES) v += ldsc(res + (size_t)row*ldc + col);
                CT* cp = C + (size_t)row*ldc + col;
                if (EPI & E_ACC) v += ldsc((const CT*)cp);
                if (EPI & E_RELU) v = fmaxf(v, 0.f);
                stsc(cp, v);
            }
        }
    }
}

// ---------- weight f32 -> bf16 hi/lo plane split (strided source) ----------
__global__ void split_kernel(const float* __restrict__ src, int ld, int cshift,
                             ushort* __restrict__ hi, ushort* __restrict__ lo, int total)
{
    const int i = blockIdx.x * 256 + threadIdx.x;
    if (i >= total) return;
    const int r = i >> cshift, c = i & ((1 << cshift) - 1);
    const float v = src[(size_t)r * ld + c];
    const ushort h = f2bf(v);
    hi[i] = h;
    lo[i] = f2bf(v - bfu(h));
}

// ---------- fused split of W1 chunk + W2 chunk (one launch per FF chunk) ----------
__global__ void split2_kernel(const float* __restrict__ s1, int ld1,
                              ushort* __restrict__ h1, ushort* __restrict__ l1, int n1,
                              const float* __restrict__ s2, int ld2,
                              ushort* __restrict__ h2, ushort* __restrict__ l2, int n2)
{
    const int i = blockIdx.x * 256 + threadIdx.x;
    if (i < n1) {
        const int r = i >> 8, c = i & 255;
        const float v = s1[(size_t)r * ld1 + c];
        const ushort h = f2bf(v);
        h1[i] = h; l1[i] = f2bf(v - bfu(h));
    } else if (i < n1 + n2) {
        const int j = i - n1;
        const int r = j >> 8, c = j & 255;
        const float v = s2[(size_t)r * ld2 + c];
        const ushort h = f2bf(v);
        h2[j] = h; l2[j] = f2bf(v - bfu(h));
    }
}

// ---------- flash attention per (b, head); K/V f32 LDS, 64-key tiles ----------
__global__ __launch_bounds__(256) void attn_kernel(const ushort* __restrict__ qkv,
                                                   ushort* __restrict__ o)
{
    __shared__ float Kf[64][68];   // 17.4 KB
    __shared__ float Vf[64][68];   // 17.4 KB  -> 34.8 KB total, 4 blocks/CU
    const int b = blockIdx.x, head = blockIdx.y;
    const ushort* base = qkv + (size_t)b * 768 + head * 64;
    const int t = threadIdx.x;
    float q[64];
    {
        const uint4* q4 = (const uint4*)(base + (size_t)t * 196608);
        #pragma unroll
        for (int w = 0; w < 8; w++) {
            const uint4 u = q4[w];
            q[8*w+0] = bf_lo(u.x)*0.125f; q[8*w+1] = bf_hi(u.x)*0.125f;
            q[8*w+2] = bf_lo(u.y)*0.125f; q[8*w+3] = bf_hi(u.y)*0.125f;
            q[8*w+4] = bf_lo(u.z)*0.125f; q[8*w+5] = bf_hi(u.z)*0.125f;
            q[8*w+6] = bf_lo(u.w)*0.125f; q[8*w+7] = bf_hi(u.w)*0.125f;
        }
    }
    float mx = -1e30f, l = 0.f;
    float oa[64];
    #pragma unroll
    for (int d = 0; d < 64; d++) oa[d] = 0.f;

    for (int kt = 0; kt < 4; kt++) {
        __syncthreads();
        #pragma unroll
        for (int i = 0; i < 2; i++) {
            const int id = i*256 + t;
            const int row = id >> 3, c8 = (id & 7) << 3;
            const ushort* rp = base + (size_t)(kt*64 + row) * 196608;
            uint4 uk = *(const uint4*)(rp + 256 + c8);
            uint4 uv = *(const uint4*)(rp + 512 + c8);
            float* kd = &Kf[row][c8];
            float* vd = &Vf[row][c8];
            kd[0]=bf_lo(uk.x); kd[1]=bf_hi(uk.x); kd[2]=bf_lo(uk.y); kd[3]=bf_hi(uk.y);
            kd[4]=bf_lo(uk.z); kd[5]=bf_hi(uk.z); kd[6]=bf_lo(uk.w); kd[7]=bf_hi(uk.w);
            vd[0]=bf_lo(uv.x); vd[1]=bf_hi(uv.x); vd[2]=bf_lo(uv.y); vd[3]=bf_hi(uv.y);
            vd[4]=bf_lo(uv.z); vd[5]=bf_hi(uv.z); vd[6]=bf_lo(uv.w); vd[7]=bf_hi(uv.w);
        }
        __syncthreads();
        for (int tp = 0; tp < 64; tp += 8) {
            float s[8];
            #pragma unroll
            for (int i = 0; i < 8; i++) {
                const float* kr = &Kf[tp + i][0];
                float a = 0.f;
                #pragma unroll
                for (int d = 0; d < 64; d++) a += q[d] * kr[d];
                s[i] = a;
            }
            float tmax = s[0];
            #pragma unroll
            for (int i = 1; i < 8; i++) tmax = fmaxf(tmax, s[i]);
            if (tmax > mx) {
                const float sc = __expf(mx - tmax);
                l *= sc;
                #pragma unroll
                for (int d = 0; d < 64; d++) oa[d] *= sc;
                mx = tmax;
            }
            #pragma unroll
            for (int i = 0; i < 8; i++) {
                const float p = __expf(s[i] - mx);
                l += p;
                const float* vr = &Vf[tp + i][0];
                #pragma unroll
                for (int d = 0; d < 64; d++) oa[d] += p * vr[d];
            }
        }
    }
    const float inv = 1.f / l;
    ushort* orow = o + (size_t)t * 65536 + b * 256 + head * 64;
    #pragma unroll
    for (int w = 0; w < 16; w++) {
        ushort4 u;
        u.x = f2bf(oa[4*w+0]*inv); u.y = f2bf(oa[4*w+1]*inv);
        u.z = f2bf(oa[4*w+2]*inv); u.w = f2bf(oa[4*w+3]*inv);
        ((ushort4*)orow)[w] = u;
    }
}

// ---------- LayerNorm over 256 features; one wave per row; optional +addin ----------
template<typename OT>
__global__ __launch_bounds__(256) void ln_kernel(const float* __restrict__ x,
    const float* __restrict__ g, const float* __restrict__ bt,
    const float* __restrict__ addin, OT* __restrict__ out, int nrows)
{
    const int gid = blockIdx.x * 256 + threadIdx.x;
    const int row = gid >> 6;
    const int lane = threadIdx.x & 63;
    if (row >= nrows) return;
    const float* xr = x + (size_t)row * 256;
    float4 v = *(const float4*)(xr + (lane<<2));
    float s = v.x + v.y + v.z + v.w;
    #pragma unroll
    for (int off = 32; off > 0; off >>= 1) s += __shfl_xor(s, off, 64);
    const float mean = s * (1.0f/256.0f);
    const float dx = v.x-mean, dy = v.y-mean, dz = v.z-mean, dw = v.w-mean;
    float ss = dx*dx + dy*dy + dz*dz + dw*dw;
    #pragma unroll
    for (int off = 32; off > 0; off >>= 1) ss += __shfl_xor(ss, off, 64);
    const float inv = rsqrtf(ss * (1.0f/256.0f) + 1e-5f);
    const float4 gv = *(const float4*)(g + (lane<<2));
    const float4 bv = *(const float4*)(bt + (lane<<2));
    float4 ov;
    ov.x = dx*inv*gv.x + bv.x;
    ov.y = dy*inv*gv.y + bv.y;
    ov.z = dz*inv*gv.z + bv.z;
    ov.w = dw*inv*gv.w + bv.w;
    if (addin) {
        const float4 av = *(const float4*)(addin + (size_t)row*256 + (lane<<2));
        ov.x+=av.x; ov.y+=av.y; ov.z+=av.z; ov.w+=av.w;
    }
    OT* op = out + (size_t)row*256 + (lane<<2);
    stsc(op+0, ov.x); stsc(op+1, ov.y); stsc(op+2, ov.z); stsc(op+3, ov.w);
}

// ---------- masked softmax over i for e[b][t][i], in place, fp32 ----------
__global__ __launch_bounds__(256) void smax_kernel(float* __restrict__ e,
                                                   const int* __restrict__ seqlen)
{
    const int gid = blockIdx.x * 256 + threadIdx.x;
    const int row = gid >> 6;               // row = b*256 + t
    const int lane = threadIdx.x & 63;
    const int L = seqlen[row >> 8];
    float* er = e + (size_t)row * 256;
    float4 v = *(const float4*)(er + (lane<<2));
    const int i0 = lane << 2;
    const float x0 = (i0+0 < L) ? v.x : -1e30f;
    const float x1 = (i0+1 < L) ? v.y : -1e30f;
    const float x2 = (i0+2 < L) ? v.z : -1e30f;
    const float x3 = (i0+3 < L) ? v.w : -1e30f;
    float mx = fmaxf(fmaxf(x0,x1), fmaxf(x2,x3));
    #pragma unroll
    for (int off = 32; off > 0; off >>= 1) mx = fmaxf(mx, __shfl_xor(mx, off, 64));
    const float p0 = (i0+0 < L) ? __expf(x0-mx) : 0.f;
    const float p1 = (i0+1 < L) ? __expf(x1-mx) : 0.f;
    const float p2 = (i0+2 < L) ? __expf(x2-mx) : 0.f;
    const float p3 = (i0+3 < L) ? __expf(x3-mx) : 0.f;
    float s = p0+p1+p2+p3;
    #pragma unroll
    for (int off = 32; off > 0; off >>= 1) s += __shfl_xor(s, off, 64);
    const float inv = 1.f / s;
    v.x = p0*inv; v.y = p1*inv; v.z = p2*inv; v.w = p3*inv;
    *(float4*)(er + (lane<<2)) = v;
}

// ---------- head: logits (512->7) + log_softmax + ragged scatter; hid bf16 ----------
__global__ __launch_bounds__(256) void head_kernel(const ushort* __restrict__ hidden,
    const float* __restrict__ Wsm, const float* __restrict__ bsm,
    const int* __restrict__ seqlen, const int* __restrict__ offs,
    float* __restrict__ out)
{
    const int gid = blockIdx.x * 256 + threadIdx.x;
    const int row = gid >> 6;
    const int lane = threadIdx.x & 63;
    if (row >= MTB) return;
    const int t = row >> 8, b = row & 255;
    if (t >= seqlen[b]) return;
    const ushort* hr = hidden + (size_t)row * 512;
    const uint4 hu = *(const uint4*)(hr + lane*8);
    float hv[8];
    hv[0]=bf_lo(hu.x); hv[1]=bf_hi(hu.x); hv[2]=bf_lo(hu.y); hv[3]=bf_hi(hu.y);
    hv[4]=bf_lo(hu.z); hv[5]=bf_hi(hu.z); hv[6]=bf_lo(hu.w); hv[7]=bf_hi(hu.w);
    float lg[7];
    #pragma unroll
    for (int c = 0; c < 7; c++) {
        const float* wr = Wsm + c*512 + lane*8;
        const float4 w0 = *(const float4*)wr;
        const float4 w1 = *(const float4*)(wr + 4);
        float acc = hv[0]*w0.x + hv[1]*w0.y + hv[2]*w0.z + hv[3]*w0.w
                  + hv[4]*w1.x + hv[5]*w1.y + hv[6]*w1.z + hv[7]*w1.w;
        #pragma unroll
        for (int off = 32; off > 0; off >>= 1) acc += __shfl_xor(acc, off, 64);
        lg[c] = acc + bsm[c];
    }
    float mx = lg[0];
    #pragma unroll
    for (int c = 1; c < 7; c++) mx = fmaxf(mx, lg[c]);
    float s = 0.f;
    #pragma unroll
    for (int c = 0; c < 7; c++) s += __expf(lg[c] - mx);
    const float lse = mx + logf(s);
    if (lane == 0) {
        float* orow = out + (size_t)(offs[b] + t) * 7;
        #pragma unroll
        for (int c = 0; c < 7; c++) orow[c] = lg[c] - lse;
    }
}

// ---------- positional encoding over the BATCH dim (faithful quirk) ----------
__global__ void pe_kernel(float* __restrict__ pe)
{
    const int idx = blockIdx.x * 256 + threadIdx.x;   // 65536 = 256x256
    const int b = idx >> 8, f = idx & 255;
    const int j = f >> 1;
    const float div = expf(-9.210340371976184f * (2.0f * j) * (1.0f/256.0f));
    const float arg = (float)b * div;
    pe[idx] = (f & 1) ? cosf(arg) : sinf(arg);
}

// ---------- exclusive prefix sum of seq lengths ----------
__global__ void prefix_kernel(const int* __restrict__ L, int* __restrict__ offs)
{
    if (threadIdx.x == 0) {
        int acc = 0;
        for (int i = 0; i < 256; i++) { offs[i] = acc; acc += L[i]; }
        offs[256] = acc;
    }
}

// ---------- diagnostic: report ws_size via absmax if insufficient ----------
__global__ void sentinel_kernel(float* __restrict__ out, float v)
{
    if (threadIdx.x == 0) out[0] = v;
}

// ---------------------------------------------------------------------------
extern "C" void kernel_launch(void* const* d_in, const int* in_sizes, int n_in,
                              void* d_out, int out_size, void* d_ws, size_t ws_size,
                              hipStream_t stream)
{
    const float* U_s   = (const float*)d_in[0];
    const float* U_p   = (const float*)d_in[1];
    const float* W_emb = (const float*)d_in[2];
    const float* b_emb = (const float*)d_in[3];
    const float* Wqkv  = (const float*)d_in[4];
    const float* bqkv  = (const float*)d_in[5];
    const float* Wo    = (const float*)d_in[6];
    const float* bo    = (const float*)d_in[7];
    const float* ln1_g = (const float*)d_in[8];
    const float* ln1_b = (const float*)d_in[9];
    const float* W1    = (const float*)d_in[10];
    const float* b1    = (const float*)d_in[11];
    const float* W2    = (const float*)d_in[12];
    const float* b2    = (const float*)d_in[13];
    const float* ln2_g = (const float*)d_in[14];
    const float* ln2_b = (const float*)d_in[15];
    const float* W_fc  = (const float*)d_in[16];
    const float* b_fc  = (const float*)d_in[17];
    const float* W_sm  = (const float*)d_in[18];
    const float* b_sm  = (const float*)d_in[19];
    const int*   seqlen= (const int*)d_in[20];
    float* out = (float*)d_out;

    // ---- aliased workspace arena, peak 193 MiB (known-good) ----
    const size_t MiB = 1024*1024;
    const size_t KiB = 1024;
    char* ws = (char*)d_ws;
    if (ws_size < 193*MiB) {
        sentinel_kernel<<<dim3(1), dim3(64), 0, stream>>>(out, -(float)(ws_size / MiB));
        return;
    }
    float*  h    = (float*)(ws);                       // [0,64M)   f32, long-lived
    int*    offs = (int*)  (ws + 64*MiB);              // 4 KiB
    char*   slot = ws + 64*MiB + 8*KiB;                // <1 MiB rotating weight-plane slot
    ushort* qkv  = (ushort*)(ws + 65*MiB);             // [65,161M)  bf16, dead after attn
    ushort* o    = (ushort*)(ws + 161*MiB);            // [161,193M) bf16, dead after proj
    float*  res1 = (float*)(ws + 65*MiB);              // [65,129M)  f32 (over dead qkv)
    float*  res2 = res1;
    ushort* h1   = (ushort*)(ws + 161*MiB);            // [161,193M) bf16 (over dead o)
    ushort* ffh  = (ushort*)(ws + 129*MiB);            // [129,161M) bf16
    float*  e    = (float*)(ws + 65*MiB);              // [65,129M)  f32 (over dead res2)
    float*  r    = (float*)(ws + 129*MiB);             // [129,193M) f32 (over dead ffh,h1)
    ushort* hid  = (ushort*)(ws + 65*MiB);             // [65,129M)  bf16 (over dead e)

    prefix_kernel<<<dim3(1), dim3(64), 0, stream>>>(seqlen, offs);

    // --- embed: split W_emb -> slot; pe -> slot+256K ---
    ushort* wh = (ushort*)slot;
    ushort* wl = (ushort*)(slot + 128*KiB);
    float*  pe = (float*)(slot + 256*KiB);             // 256 KiB
    split_kernel<<<dim3(256), 256, 0, stream>>>(W_emb, 256, 8, wh, wl, 65536);
    pe_kernel<<<dim3(256), dim3(256), 0, stream>>>(pe);
    gemm_mfma<E_BIAS|E_PE|E_MASKA, 0, 2, float, float, float>
        <<<dim3(2,512,1), 256, 0, stream>>>(
        MTB,256,256, U_s,256,0, wh,wl,256,0, h,256,0, b_emb, (const float*)nullptr, pe, seqlen);

    // --- qkv = h @ Wqkv^T + bqkv (bf16 out) ---
    wl = (ushort*)(slot + 384*KiB);
    split_kernel<<<dim3(768), 256, 0, stream>>>(Wqkv, 256, 8, wh, wl, 196608);
    gemm_mfma<E_BIAS, 0, 2, float, ushort, float>
        <<<dim3(6,512,1), 256, 0, stream>>>(
        MTB,768,256, h,256,0, wh,wl,256,0, qkv,768,0, bqkv, (const float*)nullptr, nullptr, nullptr);

    // --- attention -> o [T,B,256] bf16 ---
    attn_kernel<<<dim3(256,4), 256, 0, stream>>>(qkv, o);

    // --- res1 = o @ Wo^T + bo + h ---
    wl = (ushort*)(slot + 128*KiB);
    split_kernel<<<dim3(256), 256, 0, stream>>>(Wo, 256, 8, wh, wl, 65536);
    gemm_mfma<E_BIAS|E_RES, 1, 2, ushort, float, float>
        <<<dim3(2,512,1), 256, 0, stream>>>(
        MTB,256,256, o,256,0, wh,wl,256,0, res1,256,0, bo, h, nullptr, nullptr);

    // --- h1 = LN1(res1) (bf16 out) ---
    ln_kernel<ushort><<<dim3(MTB/4), 256, 0, stream>>>(res1, ln1_g, ln1_b, (const float*)nullptr, h1, MTB);

    // --- FF in 8 chunks of 256 over DFF=2048 ---
    ushort* w1h = (ushort*)slot;
    ushort* w1l = (ushort*)(slot + 128*KiB);
    ushort* w2h = (ushort*)(slot + 256*KiB);
    ushort* w2l = (ushort*)(slot + 384*KiB);
    for (int c = 0; c < 8; c++) {
        split2_kernel<<<dim3(512), 256, 0, stream>>>(
            W1 + (size_t)c*65536, 256, w1h, w1l, 65536,
            W2 + c*256, 2048, w2h, w2l, 65536);
        gemm_mfma<E_BIAS|E_RELU, 1, 2, ushort, ushort, float>
            <<<dim3(2,512,1), 256, 0, stream>>>(
            MTB,256,256, h1,256,0, w1h,w1l,256,0, ffh,256,0,
            b1 + c*256, (const float*)nullptr, nullptr, nullptr);
        if (c == 0)
            gemm_mfma<E_BIAS|E_RES, 1, 2, ushort, float, ushort>
                <<<dim3(2,512,1), 256, 0, stream>>>(
                MTB,256,256, ffh,256,0, w2h,w2l,256,0, res2,256,0,
                b2, h1, nullptr, nullptr);
        else
            gemm_mfma<E_ACC, 1, 2, ushort, float, float>
                <<<dim3(2,512,1), 256, 0, stream>>>(
                MTB,256,256, ffh,256,0, w2h,w2l,256,0, res2,256,0,
                nullptr, (const float*)nullptr, nullptr, nullptr);
    }

    // --- q = h + LN2(res2) (in place into h) ---
    ln_kernel<float><<<dim3(MTB/4), 256, 0, stream>>>(res2, ln2_g, ln2_b, h, h, MTB);

    // --- e[b][t][i] = q[t,b,:] . U_p[i,b,:]  (B from f32 U_p, nt) ---
    gemm_mfma<0, 0, 0, float, float, float>
        <<<dim3(2,2,256), 256, 0, stream>>>(
        256,256,256, h,65536,256, U_p,nullptr,65536,256, e,256,65536,
        nullptr, (const float*)nullptr, nullptr, nullptr);

    // --- masked softmax over i ---
    smax_kernel<<<dim3(MTB/4), 256, 0, stream>>>(e, seqlen);

    // --- r[t,b,:] = sum_i a[b][t][i] * U_p[i,b,:]  (B from f32 U_p, nn) ---
    gemm_mfma<0, 0, 1, float, float, float>
        <<<dim3(2,2,256), 256, 0, stream>>>(
        256,256,256, e,256,65536, U_p,nullptr,65536,256, r,65536,256,
        nullptr, (const float*)nullptr, nullptr, nullptr);

    // --- hidden = relu( mask(U_s)@Wfc[:,:256]^T + r@Wfc[:,256:]^T + b_fc ) (bf16) ---
    wl = (ushort*)(slot + 256*KiB);
    split_kernel<<<dim3(512), 256, 0, stream>>>(W_fc, 512, 8, wh, wl, 131072);
    gemm_mfma<E_BIAS|E_MASKA, 0, 2, float, ushort, float>
        <<<dim3(4,512,1), 256, 0, stream>>>(
        MTB,512,256, U_s,256,0, wh,wl,256,0, hid,512,0, b_fc, (const float*)nullptr, nullptr, seqlen);
    split_kernel<<<dim3(512), 256, 0, stream>>>(W_fc + 256, 512, 8, wh, wl, 131072);
    gemm_mfma<E_ACC|E_RELU, 0, 2, float, ushort, float>
        <<<dim3(4,512,1), 256, 0, stream>>>(
        MTB,512,256, r,256,0, wh,wl,256,0, hid,512,0,
        nullptr, (const float*)nullptr, nullptr, nullptr);

    // --- logits + log_softmax + ragged gather ---
    head_kernel<<<dim3(MTB/4), 256, 0, stream>>>(hid, W_sm, b_sm, seqlen, offs, out);
}

// Round 7
// 1541.718 us; speedup vs baseline: 2.6748x; 1.1134x over previous
//
#include <hip/hip_runtime.h>

#define MTB 65536   // T*B rows

typedef unsigned int uint;
typedef unsigned short ushort;

typedef _Float16 h8 __attribute__((ext_vector_type(8)));   // 8 fp16 (4 VGPR)
typedef __attribute__((ext_vector_type(4))) float f4;      // mfma accumulator

enum { E_BIAS=1, E_RELU=2, E_ACC=4, E_RES=8, E_PE=16, E_MASKA=32 };

__device__ __forceinline__ float ldsc(const float* p) { return *p; }
__device__ __forceinline__ float ldsc(const _Float16* p) { return (float)*p; }

// ---------------------------------------------------------------------------
// fp16 MFMA GEMM: C = A @ W^T (+epilogue), 128x128 tile, BK=32, 1 pass
// (3-pass split-fp16 when AMODE==3 for fp32-class output).
// AMODE: 0 = A f32 -> cvt fp16 in staging (optional MASKA)
//        2 = A fp16 stored, copy staging
//        3 = A fp16 2-plane stored (Ap hi, Ap2 lo) -> 3 passes (needs BMODE=0)
// BMODE: 0 = W f32 [N,K] -> split into 2 fp16 planes in staging
//        1 = W f32 [K,N] -> transpose + cvt single fp16
//        2 = W fp16 plane [N,K] (pre-converted), copy staging
// CPL: C written as fp16 hi/lo planes (C + cplane = lo). RPL: res is 2-plane.
// 4 waves = 2x2, each 64x64 out via 4x4 frags of 16x16x32 f16 MFMA.
// ---------------------------------------------------------------------------
template<int EPI, int AMODE, int BMODE, typename CT, int CPL, typename RT, int RPL>
__global__ __launch_bounds__(256) void gemm_h(
    int M, int N, int K,
    const void* __restrict__ Ap, const void* __restrict__ Ap2, int lda, long batchA,
    const void* __restrict__ Bp, int ldw, long batchW,
    CT* __restrict__ C, long cplane, int ldc, long batchC,
    const float* __restrict__ bias,
    const RT* __restrict__ res, const RT* __restrict__ resLo,
    const float* __restrict__ pe,
    const int* __restrict__ seqlen)
{
    __shared__ _Float16 Ah[128][40];
    __shared__ _Float16 Al[(AMODE==3)?128:1][40];
    __shared__ _Float16 Bh[128][40];
    __shared__ _Float16 Bl[(BMODE==0)?128:1][40];

    const int z = blockIdx.z;
    C += (size_t)z * batchC;
    const float*    Af  = (const float*)Ap + (AMODE==0 ? (size_t)z*batchA : 0);
    const _Float16* Ahp = (const _Float16*)Ap + (AMODE!=0 ? (size_t)z*batchA : 0);
    const _Float16* Alp = (const _Float16*)Ap2 + (AMODE==3 ? (size_t)z*batchA : 0);
    const float*    Bf  = (const float*)Bp + (BMODE!=2 ? (size_t)z*batchW : 0);
    const _Float16* Bhp = (const _Float16*)Bp;

    const int m0 = blockIdx.y * 128, n0 = blockIdx.x * 128;
    const int tid = threadIdx.x;
    const int lane = tid & 63, wid = tid >> 6;
    const int wr = wid >> 1, wc = wid & 1;

    f4 acc[4][4];
    {
        f4 zr = {0.f, 0.f, 0.f, 0.f};
        #pragma unroll
        for (int i = 0; i < 4; i++)
            #pragma unroll
            for (int j = 0; j < 4; j++) acc[i][j] = zr;
    }

    for (int k0 = 0; k0 < K; k0 += 32) {
        __syncthreads();
        // ---- stage A ----
        if (AMODE == 0) {
            #pragma unroll
            for (int i = 0; i < 4; i++) {
                const int row = i*32 + (tid>>3);
                const int cg  = (tid&7)<<2;
                const int m = m0 + row;
                float4 v; v.x=0.f; v.y=0.f; v.z=0.f; v.w=0.f;
                bool ok = true;
                if (EPI & E_MASKA) ok = ((m>>8) < seqlen[m&255]);
                if (ok) v = *(const float4*)(Af + (size_t)m*lda + k0 + cg);
                Ah[row][cg+0] = (_Float16)v.x;
                Ah[row][cg+1] = (_Float16)v.y;
                Ah[row][cg+2] = (_Float16)v.z;
                Ah[row][cg+3] = (_Float16)v.w;
            }
        } else {
            const int row = tid >> 1;
            const int cg  = (tid & 1) << 4;
            const size_t off = (size_t)(m0 + row) * lda + k0 + cg;
            *(uint4*)&Ah[row][cg]     = *(const uint4*)(Ahp + off);
            *(uint4*)&Ah[row][cg + 8] = *(const uint4*)(Ahp + off + 8);
            if (AMODE == 3) {
                *(uint4*)&Al[row][cg]     = *(const uint4*)(Alp + off);
                *(uint4*)&Al[row][cg + 8] = *(const uint4*)(Alp + off + 8);
            }
        }
        // ---- stage B ----
        if (BMODE == 2) {
            const int row = tid >> 1;
            const int cg  = (tid & 1) << 4;
            const size_t off = (size_t)(n0 + row) * ldw + k0 + cg;
            *(uint4*)&Bh[row][cg]     = *(const uint4*)(Bhp + off);
            *(uint4*)&Bh[row][cg + 8] = *(const uint4*)(Bhp + off + 8);
        } else if (BMODE == 0) {
            #pragma unroll
            for (int i = 0; i < 4; i++) {
                const int row = i*32 + (tid>>3);
                const int cg  = (tid&7)<<2;
                float4 v = *(const float4*)(Bf + (size_t)(n0+row)*ldw + k0 + cg);
                _Float16 h0 = (_Float16)v.x, h1 = (_Float16)v.y,
                         h2 = (_Float16)v.z, h3 = (_Float16)v.w;
                Bh[row][cg+0]=h0; Bl[row][cg+0]=(_Float16)(v.x-(float)h0);
                Bh[row][cg+1]=h1; Bl[row][cg+1]=(_Float16)(v.y-(float)h1);
                Bh[row][cg+2]=h2; Bl[row][cg+2]=(_Float16)(v.z-(float)h2);
                Bh[row][cg+3]=h3; Bl[row][cg+3]=(_Float16)(v.w-(float)h3);
            }
        } else {  // BMODE == 1 : W f32 [K,N], transpose + cvt
            #pragma unroll
            for (int i = 0; i < 4; i++) {
                const int kr = i*8 + (tid>>5);
                const int ng = (tid&31)<<2;
                float4 v = *(const float4*)(Bf + (size_t)(k0+kr)*ldw + n0 + ng);
                Bh[ng+0][kr] = (_Float16)v.x;
                Bh[ng+1][kr] = (_Float16)v.y;
                Bh[ng+2][kr] = (_Float16)v.z;
                Bh[ng+3][kr] = (_Float16)v.w;
            }
        }
        __syncthreads();
        // ---- fragments + MFMA ----
        const int lr = lane & 15, lk = (lane>>4)<<3;
        h8 ah[4], bh[4];
        #pragma unroll
        for (int i = 0; i < 4; i++) {
            ah[i] = *(const h8*)&Ah[wr*64 + i*16 + lr][lk];
            bh[i] = *(const h8*)&Bh[wc*64 + i*16 + lr][lk];
        }
        #pragma unroll
        for (int mi = 0; mi < 4; mi++)
            #pragma unroll
            for (int ni = 0; ni < 4; ni++)
                acc[mi][ni] = __builtin_amdgcn_mfma_f32_16x16x32_f16(ah[mi], bh[ni], acc[mi][ni], 0, 0, 0);
        if (AMODE == 3) {
            h8 al[4], bl[4];
            #pragma unroll
            for (int i = 0; i < 4; i++) {
                al[i] = *(const h8*)&Al[wr*64 + i*16 + lr][lk];
                bl[i] = *(const h8*)&Bl[wc*64 + i*16 + lr][lk];
            }
            #pragma unroll
            for (int mi = 0; mi < 4; mi++)
                #pragma unroll
                for (int ni = 0; ni < 4; ni++) {
                    acc[mi][ni] = __builtin_amdgcn_mfma_f32_16x16x32_f16(ah[mi], bl[ni], acc[mi][ni], 0, 0, 0);
                    acc[mi][ni] = __builtin_amdgcn_mfma_f32_16x16x32_f16(al[mi], bh[ni], acc[mi][ni], 0, 0, 0);
                }
        }
    }
    // ---- epilogue: C row = 4*(lane>>4)+reg, col = lane&15 ----
    const int colb = n0 + wc*64;
    const int rowb = m0 + wr*64;
    #pragma unroll
    for (int ni = 0; ni < 4; ni++) {
        const int col = colb + ni*16 + (lane & 15);
        float bv = (EPI & E_BIAS) ? bias[col] : 0.f;
        #pragma unroll
        for (int mi = 0; mi < 4; mi++) {
            const int r0 = rowb + mi*16 + ((lane>>4)<<2);
            #pragma unroll
            for (int j = 0; j < 4; j++) {
                const int row = r0 + j;
                const size_t idx = (size_t)row*ldc + col;
                float v = acc[mi][ni][j] + bv;
                if (EPI & E_PE)  v += pe[((row & 255) << 8) + col];
                if (EPI & E_RES) {
                    v += ldsc(res + idx);
                    if (RPL) v += ldsc(resLo + idx);
                }
                CT* cp = C + idx;
                if (EPI & E_ACC) v += ldsc((const CT*)cp);
                if (EPI & E_RELU) v = fmaxf(v, 0.f);
                if (CPL) {
                    _Float16 hh = (_Float16)v;
                    *(_Float16*)cp = hh;
                    *((_Float16*)cp + cplane) = (_Float16)(v - (float)hh);
                } else if (sizeof(CT) == 2) {
                    *(_Float16*)cp = (_Float16)v;
                } else {
                    *(float*)cp = v;
                }
            }
        }
    }
}

// ---------- f32 -> fp16 plane convert (strided source) ----------
__global__ void cvt_kernel(const float* __restrict__ src, int ld, int cshift,
                           _Float16* __restrict__ dst, int total)
{
    const int i = blockIdx.x * 256 + threadIdx.x;
    if (i >= total) return;
    const int r = i >> cshift, c = i & ((1 << cshift) - 1);
    dst[i] = (_Float16)src[(size_t)r * ld + c];
}

// ---------- fused convert of W1 chunk + W2 chunk ----------
__global__ void cvt2_kernel(const float* __restrict__ s1, int ld1,
                            _Float16* __restrict__ d1, int n1,
                            const float* __restrict__ s2, int ld2,
                            _Float16* __restrict__ d2, int n2)
{
    const int i = blockIdx.x * 256 + threadIdx.x;
    if (i < n1) {
        const int r = i >> 8, c = i & 255;
        d1[i] = (_Float16)s1[(size_t)r * ld1 + c];
    } else if (i < n1 + n2) {
        const int j = i - n1;
        const int r = j >> 8, c = j & 255;
        d2[j] = (_Float16)s2[(size_t)r * ld2 + c];
    }
}

// ---------- flash attention per (b, head); fp16 qkv, K/V f32 LDS ----------
__global__ __launch_bounds__(256) void attn_kernel(const _Float16* __restrict__ qkv,
                                                   _Float16* __restrict__ o)
{
    __shared__ float Kf[64][68];
    __shared__ float Vf[64][68];
    const int b = blockIdx.x, head = blockIdx.y;
    const _Float16* base = qkv + (size_t)b * 768 + head * 64;
    const int t = threadIdx.x;
    float q[64];
    {
        const h8* q8 = (const h8*)(base + (size_t)t * 196608);
        #pragma unroll
        for (int w = 0; w < 8; w++) {
            const h8 u = q8[w];
            #pragma unroll
            for (int j = 0; j < 8; j++) q[8*w+j] = (float)u[j] * 0.125f;
        }
    }
    float mx = -1e30f, l = 0.f;
    float oa[64];
    #pragma unroll
    for (int d = 0; d < 64; d++) oa[d] = 0.f;

    for (int kt = 0; kt < 4; kt++) {
        __syncthreads();
        #pragma unroll
        for (int i = 0; i < 2; i++) {
            const int id = i*256 + t;
            const int row = id >> 3, c8 = (id & 7) << 3;
            const _Float16* rp = base + (size_t)(kt*64 + row) * 196608;
            const h8 uk = *(const h8*)(rp + 256 + c8);
            const h8 uv = *(const h8*)(rp + 512 + c8);
            float* kd = &Kf[row][c8];
            float* vd = &Vf[row][c8];
            #pragma unroll
            for (int j = 0; j < 8; j++) { kd[j] = (float)uk[j]; vd[j] = (float)uv[j]; }
        }
        __syncthreads();
        for (int tp = 0; tp < 64; tp += 8) {
            float s[8];
            #pragma unroll
            for (int i = 0; i < 8; i++) {
                const float* kr = &Kf[tp + i][0];
                float a = 0.f;
                #pragma unroll
                for (int d = 0; d < 64; d++) a += q[d] * kr[d];
                s[i] = a;
            }
            float tmax = s[0];
            #pragma unroll
            for (int i = 1; i < 8; i++) tmax = fmaxf(tmax, s[i]);
            if (tmax > mx) {
                const float sc = __expf(mx - tmax);
                l *= sc;
                #pragma unroll
                for (int d = 0; d < 64; d++) oa[d] *= sc;
                mx = tmax;
            }
            #pragma unroll
            for (int i = 0; i < 8; i++) {
                const float p = __expf(s[i] - mx);
                l += p;
                const float* vr = &Vf[tp + i][0];
                #pragma unroll
                for (int d = 0; d < 64; d++) oa[d] += p * vr[d];
            }
        }
    }
    const float inv = 1.f / l;
    _Float16* orow = o + (size_t)t * 65536 + b * 256 + head * 64;
    #pragma unroll
    for (int w = 0; w < 8; w++) {
        h8 u;
        #pragma unroll
        for (int j = 0; j < 8; j++) u[j] = (_Float16)(oa[8*w+j] * inv);
        *(h8*)(orow + 8*w) = u;
    }
}

// ---------- LayerNorm; optional fp16-plane addin; f32 or fp16(/plane) out ----------
template<int OPL, typename OT>
__global__ __launch_bounds__(256) void ln_kernel(const float* __restrict__ x,
    const float* __restrict__ g, const float* __restrict__ bt,
    const _Float16* __restrict__ addin, const _Float16* __restrict__ addinLo,
    OT* __restrict__ out, long oplane, int nrows)
{
    const int gid = blockIdx.x * 256 + threadIdx.x;
    const int row = gid >> 6;
    const int lane = threadIdx.x & 63;
    if (row >= nrows) return;
    const float* xr = x + (size_t)row * 256;
    float4 v = *(const float4*)(xr + (lane<<2));
    float s = v.x + v.y + v.z + v.w;
    #pragma unroll
    for (int off = 32; off > 0; off >>= 1) s += __shfl_xor(s, off, 64);
    const float mean = s * (1.0f/256.0f);
    const float dx = v.x-mean, dy = v.y-mean, dz = v.z-mean, dw = v.w-mean;
    float ss = dx*dx + dy*dy + dz*dz + dw*dw;
    #pragma unroll
    for (int off = 32; off > 0; off >>= 1) ss += __shfl_xor(ss, off, 64);
    const float inv = rsqrtf(ss * (1.0f/256.0f) + 1e-5f);
    const float4 gv = *(const float4*)(g + (lane<<2));
    const float4 bv = *(const float4*)(bt + (lane<<2));
    float ov[4];
    ov[0] = dx*inv*gv.x + bv.x;
    ov[1] = dy*inv*gv.y + bv.y;
    ov[2] = dz*inv*gv.z + bv.z;
    ov[3] = dw*inv*gv.w + bv.w;
    const size_t base = (size_t)row*256 + (lane<<2);
    if (addin) {
        #pragma unroll
        for (int j = 0; j < 4; j++) {
            ov[j] += (float)addin[base+j];
            if (addinLo) ov[j] += (float)addinLo[base+j];
        }
    }
    #pragma unroll
    for (int j = 0; j < 4; j++) {
        if (OPL) {
            _Float16 hh = (_Float16)ov[j];
            ((_Float16*)out)[base+j] = hh;
            ((_Float16*)out)[base+j+oplane] = (_Float16)(ov[j] - (float)hh);
        } else if (sizeof(OT) == 2) {
            ((_Float16*)out)[base+j] = (_Float16)ov[j];
        } else {
            ((float*)out)[base+j] = ov[j];
        }
    }
}

// ---------- masked softmax over i for e[b][t][i], in place, fp32 ----------
__global__ __launch_bounds__(256) void smax_kernel(float* __restrict__ e,
                                                   const int* __restrict__ seqlen)
{
    const int gid = blockIdx.x * 256 + threadIdx.x;
    const int row = gid >> 6;               // row = b*256 + t
    const int lane = threadIdx.x & 63;
    const int L = seqlen[row >> 8];
    float* er = e + (size_t)row * 256;
    float4 v = *(const float4*)(er + (lane<<2));
    const int i0 = lane << 2;
    const float x0 = (i0+0 < L) ? v.x : -1e30f;
    const float x1 = (i0+1 < L) ? v.y : -1e30f;
    const float x2 = (i0+2 < L) ? v.z : -1e30f;
    const float x3 = (i0+3 < L) ? v.w : -1e30f;
    float mx = fmaxf(fmaxf(x0,x1), fmaxf(x2,x3));
    #pragma unroll
    for (int off = 32; off > 0; off >>= 1) mx = fmaxf(mx, __shfl_xor(mx, off, 64));
    const float p0 = (i0+0 < L) ? __expf(x0-mx) : 0.f;
    const float p1 = (i0+1 < L) ? __expf(x1-mx) : 0.f;
    const float p2 = (i0+2 < L) ? __expf(x2-mx) : 0.f;
    const float p3 = (i0+3 < L) ? __expf(x3-mx) : 0.f;
    float s = p0+p1+p2+p3;
    #pragma unroll
    for (int off = 32; off > 0; off >>= 1) s += __shfl_xor(s, off, 64);
    const float inv = 1.f / s;
    v.x = p0*inv; v.y = p1*inv; v.z = p2*inv; v.w = p3*inv;
    *(float4*)(er + (lane<<2)) = v;
}

// ---------- head: logits (512->7) + log_softmax + ragged scatter; hid fp16 ----------
__global__ __launch_bounds__(256) void head_kernel(const _Float16* __restrict__ hidden,
    const float* __restrict__ Wsm, const float* __restrict__ bsm,
    const int* __restrict__ seqlen, const int* __restrict__ offs,
    float* __restrict__ out)
{
    const int gid = blockIdx.x * 256 + threadIdx.x;
    const int row = gid >> 6;
    const int lane = threadIdx.x & 63;
    if (row >= MTB) return;
    const int t = row >> 8, b = row & 255;
    if (t >= seqlen[b]) return;
    const _Float16* hr = hidden + (size_t)row * 512;
    const h8 hu = *(const h8*)(hr + lane*8);
    float hv[8];
    #pragma unroll
    for (int j = 0; j < 8; j++) hv[j] = (float)hu[j];
    float lg[7];
    #pragma unroll
    for (int c = 0; c < 7; c++) {
        const float* wr = Wsm + c*512 + lane*8;
        const float4 w0 = *(const float4*)wr;
        const float4 w1 = *(const float4*)(wr + 4);
        float acc = hv[0]*w0.x + hv[1]*w0.y + hv[2]*w0.z + hv[3]*w0.w
                  + hv[4]*w1.x + hv[5]*w1.y + hv[6]*w1.z + hv[7]*w1.w;
        #pragma unroll
        for (int off = 32; off > 0; off >>= 1) acc += __shfl_xor(acc, off, 64);
        lg[c] = acc + bsm[c];
    }
    float mx = lg[0];
    #pragma unroll
    for (int c = 1; c < 7; c++) mx = fmaxf(mx, lg[c]);
    float s = 0.f;
    #pragma unroll
    for (int c = 0; c < 7; c++) s += __expf(lg[c] - mx);
    const float lse = mx + logf(s);
    if (lane == 0) {
        float* orow = out + (size_t)(offs[b] + t) * 7;
        #pragma unroll
        for (int c = 0; c < 7; c++) orow[c] = lg[c] - lse;
    }
}

// ---------- positional encoding over the BATCH dim (faithful quirk) ----------
__global__ void pe_kernel(float* __restrict__ pe)
{
    const int idx = blockIdx.x * 256 + threadIdx.x;   // 65536 = 256x256
    const int b = idx >> 8, f = idx & 255;
    const int j = f >> 1;
    const float div = expf(-9.210340371976184f * (2.0f * j) * (1.0f/256.0f));
    const float arg = (float)b * div;
    pe[idx] = (f & 1) ? cosf(arg) : sinf(arg);
}

// ---------- exclusive prefix sum of seq lengths ----------
__global__ void prefix_kernel(const int* __restrict__ L, int* __restrict__ offs)
{
    if (threadIdx.x == 0) {
        int acc = 0;
        for (int i = 0; i < 256; i++) { offs[i] = acc; acc += L[i]; }
        offs[256] = acc;
    }
}

// ---------- diagnostic: report ws_size via absmax if insufficient ----------
__global__ void sentinel_kernel(float* __restrict__ out, float v)
{
    if (threadIdx.x == 0) out[0] = v;
}

// ---------------------------------------------------------------------------
extern "C" void kernel_launch(void* const* d_in, const int* in_sizes, int n_in,
                              void* d_out, int out_size, void* d_ws, size_t ws_size,
                              hipStream_t stream)
{
    const float* U_s   = (const float*)d_in[0];
    const float* U_p   = (const float*)d_in[1];
    const float* W_emb = (const float*)d_in[2];
    const float* b_emb = (const float*)d_in[3];
    const float* Wqkv  = (const float*)d_in[4];
    const float* bqkv  = (const float*)d_in[5];
    const float* Wo    = (const float*)d_in[6];
    const float* bo    = (const float*)d_in[7];
    const float* ln1_g = (const float*)d_in[8];
    const float* ln1_b = (const float*)d_in[9];
    const float* W1    = (const float*)d_in[10];
    const float* b1    = (const float*)d_in[11];
    const float* W2    = (const float*)d_in[12];
    const float* b2    = (const float*)d_in[13];
    const float* ln2_g = (const float*)d_in[14];
    const float* ln2_b = (const float*)d_in[15];
    const float* W_fc  = (const float*)d_in[16];
    const float* b_fc  = (const float*)d_in[17];
    const float* W_sm  = (const float*)d_in[18];
    const float* b_sm  = (const float*)d_in[19];
    const int*   seqlen= (const int*)d_in[20];
    float* out = (float*)d_out;

    // ---- aliased workspace arena, peak 193 MiB ----
    const size_t MiB = 1024*1024;
    const size_t KiB = 1024;
    char* ws = (char*)d_ws;
    if (ws_size < 193*MiB) {
        sentinel_kernel<<<dim3(1), dim3(64), 0, stream>>>(out, -(float)(ws_size / MiB));
        return;
    }
    const long PL = 16*1024*1024;                        // 32 MiB plane in halves
    _Float16* h_hi = (_Float16*)(ws);                    // [0,32M)
    _Float16* h_lo = (_Float16*)(ws + 32*MiB);           // [32,64M)
    int*      offs = (int*)(ws + 64*MiB);                // 4 KiB
    char*     slot = ws + 64*MiB + 8*KiB;                // <1 MiB weight-plane slot
    _Float16* qkv  = (_Float16*)(ws + 65*MiB);           // [65,161M), dead after attn
    _Float16* o    = (_Float16*)(ws + 161*MiB);          // [161,193M), dead after proj
    float*    res1 = (float*)(ws + 65*MiB);              // [65,129M) f32 (over dead qkv)
    float*    res2 = res1;
    _Float16* h1   = (_Float16*)(ws + 161*MiB);          // [161,193M) (over dead o)
    _Float16* ffh  = (_Float16*)(ws + 129*MiB);          // [129,161M)
    _Float16* q_hi = (_Float16*)(ws + 129*MiB);          // [129,161M) (over dead ffh)
    _Float16* q_lo = (_Float16*)(ws + 161*MiB);          // [161,193M) (over dead h1)
    float*    e    = (float*)(ws + 65*MiB);              // [65,129M)  (over dead res2)
    _Float16* r    = (_Float16*)(ws);                    // [0,32M)    (over dead h planes)
    _Float16* hid  = (_Float16*)(ws + 129*MiB);          // [129,193M) (over dead q planes)

    prefix_kernel<<<dim3(1), dim3(64), 0, stream>>>(seqlen, offs);

    _Float16* wp  = (_Float16*)slot;                     // rotating weight plane
    float*    pe  = (float*)(slot + 512*KiB);            // 256 KiB, embed only

    // --- embed: h(planes) = mask(U_s) @ W_emb^T + b_emb + pe[b,:] ---
    cvt_kernel<<<dim3(256), 256, 0, stream>>>(W_emb, 256, 8, wp, 65536);
    pe_kernel<<<dim3(256), dim3(256), 0, stream>>>(pe);
    gemm_h<E_BIAS|E_PE|E_MASKA, 0, 2, _Float16, 1, float, 0>
        <<<dim3(2,512,1), 256, 0, stream>>>(
        MTB,256,256, U_s,nullptr,256,0, wp,256,0, h_hi,PL,256,0,
        b_emb, (const float*)nullptr, nullptr, pe, seqlen);

    // --- qkv = h @ Wqkv^T + bqkv (fp16) ---
    cvt_kernel<<<dim3(768), 256, 0, stream>>>(Wqkv, 256, 8, wp, 196608);
    gemm_h<E_BIAS, 2, 2, _Float16, 0, float, 0>
        <<<dim3(6,512,1), 256, 0, stream>>>(
        MTB,768,256, h_hi,nullptr,256,0, wp,256,0, qkv,0,768,0,
        bqkv, (const float*)nullptr, nullptr, nullptr, nullptr);

    // --- attention -> o [T,B,256] fp16 ---
    attn_kernel<<<dim3(256,4), 256, 0, stream>>>(qkv, o);

    // --- res1 = o @ Wo^T + bo + h(planes) ---
    cvt_kernel<<<dim3(256), 256, 0, stream>>>(Wo, 256, 8, wp, 65536);
    gemm_h<E_BIAS|E_RES, 2, 2, float, 0, _Float16, 1>
        <<<dim3(2,512,1), 256, 0, stream>>>(
        MTB,256,256, o,nullptr,256,0, wp,256,0, res1,0,256,0,
        bo, h_hi, h_lo, nullptr, nullptr);

    // --- h1 = LN1(res1) (fp16) ---
    ln_kernel<0, _Float16><<<dim3(MTB/4), 256, 0, stream>>>(
        res1, ln1_g, ln1_b, nullptr, nullptr, h1, 0, MTB);

    // --- FF in 8 chunks of 256 over DFF=2048 ---
    _Float16* w1p = (_Float16*)slot;
    _Float16* w2p = (_Float16*)(slot + 128*KiB);
    for (int c = 0; c < 8; c++) {
        cvt2_kernel<<<dim3(512), 256, 0, stream>>>(
            W1 + (size_t)c*65536, 256, w1p, 65536,
            W2 + c*256, 2048, w2p, 65536);
        gemm_h<E_BIAS|E_RELU, 2, 2, _Float16, 0, float, 0>
            <<<dim3(2,512,1), 256, 0, stream>>>(
            MTB,256,256, h1,nullptr,256,0, w1p,256,0, ffh,0,256,0,
            b1 + c*256, (const float*)nullptr, nullptr, nullptr, nullptr);
        if (c == 0)
            gemm_h<E_BIAS|E_RES, 2, 2, float, 0, _Float16, 0>
                <<<dim3(2,512,1), 256, 0, stream>>>(
                MTB,256,256, ffh,nullptr,256,0, w2p,256,0, res2,0,256,0,
                b2, h1, nullptr, nullptr, nullptr);
        else
            gemm_h<E_ACC, 2, 2, float, 0, float, 0>
                <<<dim3(2,512,1), 256, 0, stream>>>(
                MTB,256,256, ffh,nullptr,256,0, w2p,256,0, res2,0,256,0,
                nullptr, (const float*)nullptr, nullptr, nullptr, nullptr);
    }

    // --- q(planes) = h(planes) + LN2(res2) ---
    ln_kernel<1, _Float16><<<dim3(MTB/4), 256, 0, stream>>>(
        res2, ln2_g, ln2_b, h_hi, h_lo, q_hi, PL, MTB);

    // --- e[b][t][i] = q . U_p  (3-pass split-fp16, fp32-class) ---
    gemm_h<0, 3, 0, float, 0, float, 0>
        <<<dim3(2,2,256), 256, 0, stream>>>(
        256,256,256, q_hi,q_lo,65536,256, U_p,65536,256, e,0,256,65536,
        nullptr, (const float*)nullptr, nullptr, nullptr, nullptr);

    // --- masked softmax over i ---
    smax_kernel<<<dim3(MTB/4), 256, 0, stream>>>(e, seqlen);

    // --- r = a @ U_p (fp16 out) ---
    gemm_h<0, 0, 1, _Float16, 0, float, 0>
        <<<dim3(2,2,256), 256, 0, stream>>>(
        256,256,256, e,nullptr,256,65536, U_p,65536,256, r,0,65536,256,
        nullptr, (const float*)nullptr, nullptr, nullptr, nullptr);

    // --- hidden = relu( mask(U_s)@Wfc[:,:256]^T + r@Wfc[:,256:]^T + b_fc ) fp16 ---
    cvt_kernel<<<dim3(512), 256, 0, stream>>>(W_fc, 512, 8, wp, 131072);
    gemm_h<E_BIAS|E_MASKA, 0, 2, _Float16, 0, float, 0>
        <<<dim3(4,512,1), 256, 0, stream>>>(
        MTB,512,256, U_s,nullptr,256,0, wp,256,0, hid,0,512,0,
        b_fc, (const float*)nullptr, nullptr, nullptr, seqlen);
    cvt_kernel<<<dim3(512), 256, 0, stream>>>(W_fc + 256, 512, 8, wp, 131072);
    gemm_h<E_ACC|E_RELU, 2, 2, _Float16, 0, float, 0>
        <<<dim3(4,512,1), 256, 0, stream>>>(
        MTB,512,256, r,nullptr,256,0, wp,256,0, hid,0,512,0,
        nullptr, (const float*)nullptr, nullptr, nullptr, nullptr);

    // --- logits + log_softmax + ragged gather ---
    head_kernel<<<dim3(MTB/4), 256, 0, stream>>>(hid, W_sm, b_sm, seqlen, offs, out);
}

// Round 8
// 1158.604 us; speedup vs baseline: 3.5593x; 1.3307x over previous
//
#include <hip/hip_runtime.h>

#define MTB 65536   // T*B rows

typedef unsigned int uint;
typedef unsigned short ushort;

typedef _Float16 h8 __attribute__((ext_vector_type(8)));   // 8 fp16 (4 VGPR)
typedef __attribute__((ext_vector_type(4))) float f4;      // mfma accumulator

enum { E_BIAS=1, E_RELU=2, E_ACC=4, E_RES=8, E_PE=16, E_MASKA=32 };

__device__ __forceinline__ float ldsc(const float* p) { return *p; }
__device__ __forceinline__ float ldsc(const _Float16* p) { return (float)*p; }

// ---------------------------------------------------------------------------
// fp16 MFMA GEMM: C = A @ W^T (+epilogue), 128x128 tile, BK=32.
// AMODE: 0 = A f32 -> cvt fp16 in staging (optional MASKA)
//        2 = A fp16 stored, copy staging
//        3 = A fp16 2-plane stored (Ap hi, Ap2 lo) -> 3 passes (needs BMODE=0)
//        4 = hybrid K=512: k<256 from f32 Ap (masked), k>=256 from fp16 Ap2
// BMODE: 0 = W f32 [N,K] -> split into 2 fp16 planes in staging
//        1 = W f32 [K,N] -> transpose + cvt single fp16
//        2 = W fp16 plane [N,K] (pre-converted), copy staging
// CPL: C written as fp16 hi/lo planes (C + cplane = lo). RPL: res is 2-plane.
// ---------------------------------------------------------------------------
template<int EPI, int AMODE, int BMODE, typename CT, int CPL, typename RT, int RPL>
__global__ __launch_bounds__(256) void gemm_h(
    int M, int N, int K,
    const void* __restrict__ Ap, const void* __restrict__ Ap2, int lda, long batchA,
    const void* __restrict__ Bp, int ldw, long batchW,
    CT* __restrict__ C, long cplane, int ldc, long batchC,
    const float* __restrict__ bias,
    const RT* __restrict__ res, const RT* __restrict__ resLo,
    const float* __restrict__ pe,
    const int* __restrict__ seqlen)
{
    __shared__ _Float16 Ah[128][40];
    __shared__ _Float16 Al[(AMODE==3)?128:1][40];
    __shared__ _Float16 Bh[128][40];
    __shared__ _Float16 Bl[(BMODE==0)?128:1][40];

    const int z = blockIdx.z;
    C += (size_t)z * batchC;
    const float*    Af  = (const float*)Ap + (AMODE==0 ? (size_t)z*batchA : 0);
    const _Float16* Ahp = (const _Float16*)Ap + ((AMODE==2||AMODE==3) ? (size_t)z*batchA : 0);
    const _Float16* Alp = (const _Float16*)Ap2 + (AMODE==3 ? (size_t)z*batchA : 0);
    const float*    Bf  = (const float*)Bp + (BMODE!=2 ? (size_t)z*batchW : 0);
    const _Float16* Bhp = (const _Float16*)Bp;

    const int m0 = blockIdx.y * 128, n0 = blockIdx.x * 128;
    const int tid = threadIdx.x;
    const int lane = tid & 63, wid = tid >> 6;
    const int wr = wid >> 1, wc = wid & 1;

    f4 acc[4][4];
    {
        f4 zr = {0.f, 0.f, 0.f, 0.f};
        #pragma unroll
        for (int i = 0; i < 4; i++)
            #pragma unroll
            for (int j = 0; j < 4; j++) acc[i][j] = zr;
    }

    for (int k0 = 0; k0 < K; k0 += 32) {
        __syncthreads();
        // ---- stage A ----
        if (AMODE == 0 || (AMODE == 4 && k0 < 256)) {
            #pragma unroll
            for (int i = 0; i < 4; i++) {
                const int row = i*32 + (tid>>3);
                const int cg  = (tid&7)<<2;
                const int m = m0 + row;
                float4 v; v.x=0.f; v.y=0.f; v.z=0.f; v.w=0.f;
                bool ok = true;
                if (EPI & E_MASKA) ok = ((m>>8) < seqlen[m&255]);
                if (ok) v = *(const float4*)(Af + (size_t)m*lda + k0 + cg);
                Ah[row][cg+0] = (_Float16)v.x;
                Ah[row][cg+1] = (_Float16)v.y;
                Ah[row][cg+2] = (_Float16)v.z;
                Ah[row][cg+3] = (_Float16)v.w;
            }
        } else if (AMODE == 4) {
            const _Float16* Ar = (const _Float16*)Ap2;
            const int row = tid >> 1;
            const int cg  = (tid & 1) << 4;
            const size_t off = (size_t)(m0 + row) * 256 + (k0 - 256) + cg;
            *(uint4*)&Ah[row][cg]     = *(const uint4*)(Ar + off);
            *(uint4*)&Ah[row][cg + 8] = *(const uint4*)(Ar + off + 8);
        } else {
            const int row = tid >> 1;
            const int cg  = (tid & 1) << 4;
            const size_t off = (size_t)(m0 + row) * lda + k0 + cg;
            *(uint4*)&Ah[row][cg]     = *(const uint4*)(Ahp + off);
            *(uint4*)&Ah[row][cg + 8] = *(const uint4*)(Ahp + off + 8);
            if (AMODE == 3) {
                *(uint4*)&Al[row][cg]     = *(const uint4*)(Alp + off);
                *(uint4*)&Al[row][cg + 8] = *(const uint4*)(Alp + off + 8);
            }
        }
        // ---- stage B ----
        if (BMODE == 2) {
            const int row = tid >> 1;
            const int cg  = (tid & 1) << 4;
            const size_t off = (size_t)(n0 + row) * ldw + k0 + cg;
            *(uint4*)&Bh[row][cg]     = *(const uint4*)(Bhp + off);
            *(uint4*)&Bh[row][cg + 8] = *(const uint4*)(Bhp + off + 8);
        } else if (BMODE == 0) {
            #pragma unroll
            for (int i = 0; i < 4; i++) {
                const int row = i*32 + (tid>>3);
                const int cg  = (tid&7)<<2;
                float4 v = *(const float4*)(Bf + (size_t)(n0+row)*ldw + k0 + cg);
                _Float16 h0 = (_Float16)v.x, h1 = (_Float16)v.y,
                         h2 = (_Float16)v.z, h3 = (_Float16)v.w;
                Bh[row][cg+0]=h0; Bl[row][cg+0]=(_Float16)(v.x-(float)h0);
                Bh[row][cg+1]=h1; Bl[row][cg+1]=(_Float16)(v.y-(float)h1);
                Bh[row][cg+2]=h2; Bl[row][cg+2]=(_Float16)(v.z-(float)h2);
                Bh[row][cg+3]=h3; Bl[row][cg+3]=(_Float16)(v.w-(float)h3);
            }
        } else {  // BMODE == 1 : W f32 [K,N], transpose + cvt
            #pragma unroll
            for (int i = 0; i < 4; i++) {
                const int kr = i*8 + (tid>>5);
                const int ng = (tid&31)<<2;
                float4 v = *(const float4*)(Bf + (size_t)(k0+kr)*ldw + n0 + ng);
                Bh[ng+0][kr] = (_Float16)v.x;
                Bh[ng+1][kr] = (_Float16)v.y;
                Bh[ng+2][kr] = (_Float16)v.z;
                Bh[ng+3][kr] = (_Float16)v.w;
            }
        }
        __syncthreads();
        // ---- fragments + MFMA ----
        const int lr = lane & 15, lk = (lane>>4)<<3;
        h8 ah[4], bh[4];
        #pragma unroll
        for (int i = 0; i < 4; i++) {
            ah[i] = *(const h8*)&Ah[wr*64 + i*16 + lr][lk];
            bh[i] = *(const h8*)&Bh[wc*64 + i*16 + lr][lk];
        }
        #pragma unroll
        for (int mi = 0; mi < 4; mi++)
            #pragma unroll
            for (int ni = 0; ni < 4; ni++)
                acc[mi][ni] = __builtin_amdgcn_mfma_f32_16x16x32_f16(ah[mi], bh[ni], acc[mi][ni], 0, 0, 0);
        if (AMODE == 3) {
            h8 al[4], bl[4];
            #pragma unroll
            for (int i = 0; i < 4; i++) {
                al[i] = *(const h8*)&Al[wr*64 + i*16 + lr][lk];
                bl[i] = *(const h8*)&Bl[wc*64 + i*16 + lr][lk];
            }
            #pragma unroll
            for (int mi = 0; mi < 4; mi++)
                #pragma unroll
                for (int ni = 0; ni < 4; ni++) {
                    acc[mi][ni] = __builtin_amdgcn_mfma_f32_16x16x32_f16(ah[mi], bl[ni], acc[mi][ni], 0, 0, 0);
                    acc[mi][ni] = __builtin_amdgcn_mfma_f32_16x16x32_f16(al[mi], bh[ni], acc[mi][ni], 0, 0, 0);
                }
        }
    }
    // ---- epilogue: C row = 4*(lane>>4)+reg, col = lane&15 ----
    const int colb = n0 + wc*64;
    const int rowb = m0 + wr*64;
    #pragma unroll
    for (int ni = 0; ni < 4; ni++) {
        const int col = colb + ni*16 + (lane & 15);
        float bv = (EPI & E_BIAS) ? bias[col] : 0.f;
        #pragma unroll
        for (int mi = 0; mi < 4; mi++) {
            const int r0 = rowb + mi*16 + ((lane>>4)<<2);
            #pragma unroll
            for (int j = 0; j < 4; j++) {
                const int row = r0 + j;
                const size_t idx = (size_t)row*ldc + col;
                float v = acc[mi][ni][j] + bv;
                if (EPI & E_PE)  v += pe[((row & 255) << 8) + col];
                if (EPI & E_RES) {
                    v += ldsc(res + idx);
                    if (RPL) v += ldsc(resLo + idx);
                }
                CT* cp = C + idx;
                if (EPI & E_ACC) v += ldsc((const CT*)cp);
                if (EPI & E_RELU) v = fmaxf(v, 0.f);
                if (CPL) {
                    _Float16 hh = (_Float16)v;
                    *(_Float16*)cp = hh;
                    *((_Float16*)cp + cplane) = (_Float16)(v - (float)hh);
                } else if (sizeof(CT) == 2) {
                    *(_Float16*)cp = (_Float16)v;
                } else {
                    *(float*)cp = v;
                }
            }
        }
    }
}

// ---------------------------------------------------------------------------
// Fused FF: res2 = h1 + relu(h1 @ W1^T + b1) @ W2^T + b2, per 64-row tile,
// DFF accumulated in f32 registers (no global round trips).
// 4 waves 2x2; acc2: 32 rows x 128 cols per wave (2x8 frags).
// ---------------------------------------------------------------------------
__global__ __launch_bounds__(256) void ff_kernel(
    const _Float16* __restrict__ h1,    // [65536][256]
    const _Float16* __restrict__ W1p,   // [2048][256] fp16
    const _Float16* __restrict__ W2p,   // [256][2048] fp16
    const float* __restrict__ b1,
    const float* __restrict__ b2,
    float* __restrict__ res2)           // [65536][256]
{
    __shared__ _Float16 h1t[64][264];   // 33.8 KB
    __shared__ _Float16 zt[64][136];    // 17.4 KB
    __shared__ _Float16 Bs[256][40];    // 20.5 KB
    const int m0 = blockIdx.x * 64;
    const int tid = threadIdx.x;
    const int lane = tid & 63, wid = tid >> 6;
    const int wr = wid >> 1, wc = wid & 1;
    const int lr = lane & 15, lk = (lane >> 4) << 3;
    const int l4 = (lane >> 4) << 2;

    // stage h1 tile 64x256 fp16
    {
        const int row = tid >> 2, c0 = (tid & 3) << 6;
        const _Float16* src = h1 + (size_t)(m0 + row) * 256 + c0;
        #pragma unroll
        for (int j = 0; j < 8; j++)
            *(uint4*)&h1t[row][c0 + 8*j] = *(const uint4*)(src + 8*j);
    }

    f4 acc2[2][8];
    {
        f4 zr = {0.f,0.f,0.f,0.f};
        #pragma unroll
        for (int mi = 0; mi < 2; mi++)
            #pragma unroll
            for (int ni = 0; ni < 8; ni++) acc2[mi][ni] = zr;
    }

    for (int c = 0; c < 16; c++) {
        // ---- GEMM1: z = relu(h1t @ W1c^T + b1c), 64 x 128 ----
        f4 acc1[2][4];
        {
            f4 zr = {0.f,0.f,0.f,0.f};
            #pragma unroll
            for (int mi = 0; mi < 2; mi++)
                #pragma unroll
                for (int ni = 0; ni < 4; ni++) acc1[mi][ni] = zr;
        }
        for (int k0 = 0; k0 < 256; k0 += 32) {
            __syncthreads();
            {   // stage W1 tile [128][32]
                const int row = tid >> 1, cc = (tid & 1) << 4;
                const size_t off = (size_t)(c*128 + row) * 256 + k0 + cc;
                *(uint4*)&Bs[row][cc]   = *(const uint4*)(W1p + off);
                *(uint4*)&Bs[row][cc+8] = *(const uint4*)(W1p + off + 8);
            }
            __syncthreads();
            h8 a0 = *(const h8*)&h1t[wr*32 +      lr][k0 + lk];
            h8 a1 = *(const h8*)&h1t[wr*32 + 16 + lr][k0 + lk];
            #pragma unroll
            for (int ni = 0; ni < 4; ni++) {
                const h8 b = *(const h8*)&Bs[wc*64 + ni*16 + lr][lk];
                acc1[0][ni] = __builtin_amdgcn_mfma_f32_16x16x32_f16(a0, b, acc1[0][ni], 0, 0, 0);
                acc1[1][ni] = __builtin_amdgcn_mfma_f32_16x16x32_f16(a1, b, acc1[1][ni], 0, 0, 0);
            }
        }
        // write z to LDS with bias+relu  (zt reads of prev chunk fenced by GEMM1 barriers)
        #pragma unroll
        for (int ni = 0; ni < 4; ni++) {
            const float bv = b1[c*128 + wc*64 + ni*16 + lr];
            #pragma unroll
            for (int mi = 0; mi < 2; mi++)
                #pragma unroll
                for (int j = 0; j < 4; j++) {
                    float v = acc1[mi][ni][j] + bv;
                    v = fmaxf(v, 0.f);
                    zt[wr*32 + mi*16 + l4 + j][wc*64 + ni*16 + lr] = (_Float16)v;
                }
        }
        __syncthreads();
        // ---- GEMM2: acc2 += zt @ W2c^T, K = 128 ----
        for (int kk = 0; kk < 128; kk += 32) {
            if (kk) __syncthreads();
            {   // stage W2 tile [256][32]
                const size_t off = (size_t)tid * 2048 + c*128 + kk;
                #pragma unroll
                for (int j = 0; j < 4; j++)
                    *(uint4*)&Bs[tid][8*j] = *(const uint4*)(W2p + off + 8*j);
            }
            __syncthreads();
            h8 a0 = *(const h8*)&zt[wr*32 +      lr][kk + lk];
            h8 a1 = *(const h8*)&zt[wr*32 + 16 + lr][kk + lk];
            #pragma unroll
            for (int ni = 0; ni < 8; ni++) {
                const h8 b = *(const h8*)&Bs[wc*128 + ni*16 + lr][lk];
                acc2[0][ni] = __builtin_amdgcn_mfma_f32_16x16x32_f16(a0, b, acc2[0][ni], 0, 0, 0);
                acc2[1][ni] = __builtin_amdgcn_mfma_f32_16x16x32_f16(a1, b, acc2[1][ni], 0, 0, 0);
            }
        }
        __syncthreads();   // protect zt before next chunk's writes
    }
    // ---- epilogue: res2 = acc2 + b2 + h1 residual ----
    #pragma unroll
    for (int ni = 0; ni < 8; ni++) {
        const int col = wc*128 + ni*16 + lr;
        const float bv = b2[col];
        #pragma unroll
        for (int mi = 0; mi < 2; mi++) {
            const int rl = wr*32 + mi*16 + l4;
            #pragma unroll
            for (int j = 0; j < 4; j++) {
                float v = acc2[mi][ni][j] + bv + (float)h1t[rl + j][col];
                res2[(size_t)(m0 + rl + j) * 256 + col] = v;
            }
        }
    }
}

// ---------- f32 -> fp16 plane convert (strided source) ----------
__global__ void cvt_kernel(const float* __restrict__ src, int ld, int cshift,
                           _Float16* __restrict__ dst, int total)
{
    const int i = blockIdx.x * 256 + threadIdx.x;
    if (i >= total) return;
    const int r = i >> cshift, c = i & ((1 << cshift) - 1);
    dst[i] = (_Float16)src[(size_t)r * ld + c];
}

// ---------- flash attention per (b, head); fp16 qkv, K/V f32 LDS ----------
__global__ __launch_bounds__(256) void attn_kernel(const _Float16* __restrict__ qkv,
                                                   _Float16* __restrict__ o)
{
    __shared__ float Kf[64][68];
    __shared__ float Vf[64][68];
    const int b = blockIdx.x, head = blockIdx.y;
    const _Float16* base = qkv + (size_t)b * 768 + head * 64;
    const int t = threadIdx.x;
    float q[64];
    {
        const h8* q8 = (const h8*)(base + (size_t)t * 196608);
        #pragma unroll
        for (int w = 0; w < 8; w++) {
            const h8 u = q8[w];
            #pragma unroll
            for (int j = 0; j < 8; j++) q[8*w+j] = (float)u[j] * 0.125f;
        }
    }
    float mx = -1e30f, l = 0.f;
    float oa[64];
    #pragma unroll
    for (int d = 0; d < 64; d++) oa[d] = 0.f;

    for (int kt = 0; kt < 4; kt++) {
        __syncthreads();
        #pragma unroll
        for (int i = 0; i < 2; i++) {
            const int id = i*256 + t;
            const int row = id >> 3, c8 = (id & 7) << 3;
            const _Float16* rp = base + (size_t)(kt*64 + row) * 196608;
            const h8 uk = *(const h8*)(rp + 256 + c8);
            const h8 uv = *(const h8*)(rp + 512 + c8);
            float* kd = &Kf[row][c8];
            float* vd = &Vf[row][c8];
            #pragma unroll
            for (int j = 0; j < 8; j++) { kd[j] = (float)uk[j]; vd[j] = (float)uv[j]; }
        }
        __syncthreads();
        for (int tp = 0; tp < 64; tp += 8) {
            float s[8];
            #pragma unroll
            for (int i = 0; i < 8; i++) {
                const float* kr = &Kf[tp + i][0];
                float a = 0.f;
                #pragma unroll
                for (int d = 0; d < 64; d++) a += q[d] * kr[d];
                s[i] = a;
            }
            float tmax = s[0];
            #pragma unroll
            for (int i = 1; i < 8; i++) tmax = fmaxf(tmax, s[i]);
            if (tmax > mx) {
                const float sc = __expf(mx - tmax);
                l *= sc;
                #pragma unroll
                for (int d = 0; d < 64; d++) oa[d] *= sc;
                mx = tmax;
            }
            #pragma unroll
            for (int i = 0; i < 8; i++) {
                const float p = __expf(s[i] - mx);
                l += p;
                const float* vr = &Vf[tp + i][0];
                #pragma unroll
                for (int d = 0; d < 64; d++) oa[d] += p * vr[d];
            }
        }
    }
    const float inv = 1.f / l;
    _Float16* orow = o + (size_t)t * 65536 + b * 256 + head * 64;
    #pragma unroll
    for (int w = 0; w < 8; w++) {
        h8 u;
        #pragma unroll
        for (int j = 0; j < 8; j++) u[j] = (_Float16)(oa[8*w+j] * inv);
        *(h8*)(orow + 8*w) = u;
    }
}

// ---------- LayerNorm; optional fp16-plane addin; f32 or fp16(/plane) out ----------
template<int OPL, typename OT>
__global__ __launch_bounds__(256) void ln_kernel(const float* __restrict__ x,
    const float* __restrict__ g, const float* __restrict__ bt,
    const _Float16* __restrict__ addin, const _Float16* __restrict__ addinLo,
    OT* __restrict__ out, long oplane, int nrows)
{
    const int gid = blockIdx.x * 256 + threadIdx.x;
    const int row = gid >> 6;
    const int lane = threadIdx.x & 63;
    if (row >= nrows) return;
    const float* xr = x + (size_t)row * 256;
    float4 v = *(const float4*)(xr + (lane<<2));
    float s = v.x + v.y + v.z + v.w;
    #pragma unroll
    for (int off = 32; off > 0; off >>= 1) s += __shfl_xor(s, off, 64);
    const float mean = s * (1.0f/256.0f);
    const float dx = v.x-mean, dy = v.y-mean, dz = v.z-mean, dw = v.w-mean;
    float ss = dx*dx + dy*dy + dz*dz + dw*dw;
    #pragma unroll
    for (int off = 32; off > 0; off >>= 1) ss += __shfl_xor(ss, off, 64);
    const float inv = rsqrtf(ss * (1.0f/256.0f) + 1e-5f);
    const float4 gv = *(const float4*)(g + (lane<<2));
    const float4 bv = *(const float4*)(bt + (lane<<2));
    float ov[4];
    ov[0] = dx*inv*gv.x + bv.x;
    ov[1] = dy*inv*gv.y + bv.y;
    ov[2] = dz*inv*gv.z + bv.z;
    ov[3] = dw*inv*gv.w + bv.w;
    const size_t base = (size_t)row*256 + (lane<<2);
    if (addin) {
        #pragma unroll
        for (int j = 0; j < 4; j++) {
            ov[j] += (float)addin[base+j];
            if (addinLo) ov[j] += (float)addinLo[base+j];
        }
    }
    #pragma unroll
    for (int j = 0; j < 4; j++) {
        if (OPL) {
            _Float16 hh = (_Float16)ov[j];
            ((_Float16*)out)[base+j] = hh;
            ((_Float16*)out)[base+j+oplane] = (_Float16)(ov[j] - (float)hh);
        } else if (sizeof(OT) == 2) {
            ((_Float16*)out)[base+j] = (_Float16)ov[j];
        } else {
            ((float*)out)[base+j] = ov[j];
        }
    }
}

// ---------- masked softmax over i for e[b][t][i], in place, fp32 ----------
__global__ __launch_bounds__(256) void smax_kernel(float* __restrict__ e,
                                                   const int* __restrict__ seqlen)
{
    const int gid = blockIdx.x * 256 + threadIdx.x;
    const int row = gid >> 6;               // row = b*256 + t
    const int lane = threadIdx.x & 63;
    const int L = seqlen[row >> 8];
    float* er = e + (size_t)row * 256;
    float4 v = *(const float4*)(er + (lane<<2));
    const int i0 = lane << 2;
    const float x0 = (i0+0 < L) ? v.x : -1e30f;
    const float x1 = (i0+1 < L) ? v.y : -1e30f;
    const float x2 = (i0+2 < L) ? v.z : -1e30f;
    const float x3 = (i0+3 < L) ? v.w : -1e30f;
    float mx = fmaxf(fmaxf(x0,x1), fmaxf(x2,x3));
    #pragma unroll
    for (int off = 32; off > 0; off >>= 1) mx = fmaxf(mx, __shfl_xor(mx, off, 64));
    const float p0 = (i0+0 < L) ? __expf(x0-mx) : 0.f;
    const float p1 = (i0+1 < L) ? __expf(x1-mx) : 0.f;
    const float p2 = (i0+2 < L) ? __expf(x2-mx) : 0.f;
    const float p3 = (i0+3 < L) ? __expf(x3-mx) : 0.f;
    float s = p0+p1+p2+p3;
    #pragma unroll
    for (int off = 32; off > 0; off >>= 1) s += __shfl_xor(s, off, 64);
    const float inv = 1.f / s;
    v.x = p0*inv; v.y = p1*inv; v.z = p2*inv; v.w = p3*inv;
    *(float4*)(er + (lane<<2)) = v;
}

// ---------- head: logits (512->7) + log_softmax + ragged scatter; hid fp16 ----------
__global__ __launch_bounds__(256) void head_kernel(const _Float16* __restrict__ hidden,
    const float* __restrict__ Wsm, const float* __restrict__ bsm,
    const int* __restrict__ seqlen, const int* __restrict__ offs,
    float* __restrict__ out)
{
    const int gid = blockIdx.x * 256 + threadIdx.x;
    const int row = gid >> 6;
    const int lane = threadIdx.x & 63;
    if (row >= MTB) return;
    const int t = row >> 8, b = row & 255;
    if (t >= seqlen[b]) return;
    const _Float16* hr = hidden + (size_t)row * 512;
    const h8 hu = *(const h8*)(hr + lane*8);
    float hv[8];
    #pragma unroll
    for (int j = 0; j < 8; j++) hv[j] = (float)hu[j];
    float lg[7];
    #pragma unroll
    for (int c = 0; c < 7; c++) {
        const float* wr = Wsm + c*512 + lane*8;
        const float4 w0 = *(const float4*)wr;
        const float4 w1 = *(const float4*)(wr + 4);
        float acc = hv[0]*w0.x + hv[1]*w0.y + hv[2]*w0.z + hv[3]*w0.w
                  + hv[4]*w1.x + hv[5]*w1.y + hv[6]*w1.z + hv[7]*w1.w;
        #pragma unroll
        for (int off = 32; off > 0; off >>= 1) acc += __shfl_xor(acc, off, 64);
        lg[c] = acc + bsm[c];
    }
    float mx = lg[0];
    #pragma unroll
    for (int c = 1; c < 7; c++) mx = fmaxf(mx, lg[c]);
    float s = 0.f;
    #pragma unroll
    for (int c = 0; c < 7; c++) s += __expf(lg[c] - mx);
    const float lse = mx + logf(s);
    if (lane == 0) {
        float* orow = out + (size_t)(offs[b] + t) * 7;
        #pragma unroll
        for (int c = 0; c < 7; c++) orow[c] = lg[c] - lse;
    }
}

// ---------- positional encoding over the BATCH dim (faithful quirk) ----------
__global__ void pe_kernel(float* __restrict__ pe)
{
    const int idx = blockIdx.x * 256 + threadIdx.x;   // 65536 = 256x256
    const int b = idx >> 8, f = idx & 255;
    const int j = f >> 1;
    const float div = expf(-9.210340371976184f * (2.0f * j) * (1.0f/256.0f));
    const float arg = (float)b * div;
    pe[idx] = (f & 1) ? cosf(arg) : sinf(arg);
}

// ---------- exclusive prefix sum of seq lengths ----------
__global__ void prefix_kernel(const int* __restrict__ L, int* __restrict__ offs)
{
    if (threadIdx.x == 0) {
        int acc = 0;
        for (int i = 0; i < 256; i++) { offs[i] = acc; acc += L[i]; }
        offs[256] = acc;
    }
}

// ---------- diagnostic: report ws_size via absmax if insufficient ----------
__global__ void sentinel_kernel(float* __restrict__ out, float v)
{
    if (threadIdx.x == 0) out[0] = v;
}

// ---------------------------------------------------------------------------
extern "C" void kernel_launch(void* const* d_in, const int* in_sizes, int n_in,
                              void* d_out, int out_size, void* d_ws, size_t ws_size,
                              hipStream_t stream)
{
    const float* U_s   = (const float*)d_in[0];
    const float* U_p   = (const float*)d_in[1];
    const float* W_emb = (const float*)d_in[2];
    const float* b_emb = (const float*)d_in[3];
    const float* Wqkv  = (const float*)d_in[4];
    const float* bqkv  = (const float*)d_in[5];
    const float* Wo    = (const float*)d_in[6];
    const float* bo    = (const float*)d_in[7];
    const float* ln1_g = (const float*)d_in[8];
    const float* ln1_b = (const float*)d_in[9];
    const float* W1    = (const float*)d_in[10];
    const float* b1    = (const float*)d_in[11];
    const float* W2    = (const float*)d_in[12];
    const float* b2    = (const float*)d_in[13];
    const float* ln2_g = (const float*)d_in[14];
    const float* ln2_b = (const float*)d_in[15];
    const float* W_fc  = (const float*)d_in[16];
    const float* b_fc  = (const float*)d_in[17];
    const float* W_sm  = (const float*)d_in[18];
    const float* b_sm  = (const float*)d_in[19];
    const int*   seqlen= (const int*)d_in[20];
    float* out = (float*)d_out;

    // ---- aliased workspace arena, peak 193 MiB ----
    const size_t MiB = 1024*1024;
    const size_t KiB = 1024;
    char* ws = (char*)d_ws;
    if (ws_size < 193*MiB) {
        sentinel_kernel<<<dim3(1), dim3(64), 0, stream>>>(out, -(float)(ws_size / MiB));
        return;
    }
    const long PL = 16*1024*1024;                        // plane stride (elems)
    _Float16* h_hi = (_Float16*)(ws);                    // [0,32M)
    _Float16* h_lo = (_Float16*)(ws + 32*MiB);           // [32,64M)
    int*      offs = (int*)(ws + 64*MiB);                // 4 KiB
    char*     slot = ws + 64*MiB + 8*KiB;                // <1 MiB weight slot
    _Float16* qkv  = (_Float16*)(ws + 65*MiB);           // [65,161M), dead after attn
    _Float16* o    = (_Float16*)(ws + 161*MiB);          // [161,193M), dead after proj
    float*    res1 = (float*)(ws + 65*MiB);              // [65,129M) f32 (over dead qkv)
    float*    res2 = res1;
    _Float16* h1   = (_Float16*)(ws + 161*MiB);          // [161,193M) (over dead o)
    _Float16* w1p  = (_Float16*)(ws + 129*MiB);          // [129,130M) FF weights (fp16)
    _Float16* w2p  = (_Float16*)(ws + 130*MiB);          // [130,131M)
    _Float16* q_hi = (_Float16*)(ws + 129*MiB);          // [129,161M) (over dead w1p/w2p)
    _Float16* q_lo = (_Float16*)(ws + 161*MiB);          // [161,193M) (over dead h1)
    float*    e    = (float*)(ws + 65*MiB);              // [65,129M)  (over dead res2)
    _Float16* r    = (_Float16*)(ws);                    // [0,32M)    (over dead h planes)
    _Float16* hid  = (_Float16*)(ws + 129*MiB);          // [129,193M) (over dead q planes)

    prefix_kernel<<<dim3(1), dim3(64), 0, stream>>>(seqlen, offs);

    _Float16* wp  = (_Float16*)slot;                     // rotating weight plane
    float*    pe  = (float*)(slot + 512*KiB);            // 256 KiB, embed only

    // --- embed: h(planes) = mask(U_s) @ W_emb^T + b_emb + pe[b,:] ---
    cvt_kernel<<<dim3(256), 256, 0, stream>>>(W_emb, 256, 8, wp, 65536);
    pe_kernel<<<dim3(256), dim3(256), 0, stream>>>(pe);
    gemm_h<E_BIAS|E_PE|E_MASKA, 0, 2, _Float16, 1, float, 0>
        <<<dim3(2,512,1), 256, 0, stream>>>(
        MTB,256,256, U_s,nullptr,256,0, wp,256,0, h_hi,PL,256,0,
        b_emb, (const float*)nullptr, nullptr, pe, seqlen);

    // --- qkv = h @ Wqkv^T + bqkv (fp16) ---
    cvt_kernel<<<dim3(768), 256, 0, stream>>>(Wqkv, 256, 8, wp, 196608);
    gemm_h<E_BIAS, 2, 2, _Float16, 0, float, 0>
        <<<dim3(6,512,1), 256, 0, stream>>>(
        MTB,768,256, h_hi,nullptr,256,0, wp,256,0, qkv,0,768,0,
        bqkv, (const float*)nullptr, nullptr, nullptr, nullptr);

    // --- attention -> o [T,B,256] fp16 ---
    attn_kernel<<<dim3(256,4), 256, 0, stream>>>(qkv, o);

    // --- res1 = o @ Wo^T + bo + h(planes) ---
    cvt_kernel<<<dim3(256), 256, 0, stream>>>(Wo, 256, 8, wp, 65536);
    gemm_h<E_BIAS|E_RES, 2, 2, float, 0, _Float16, 1>
        <<<dim3(2,512,1), 256, 0, stream>>>(
        MTB,256,256, o,nullptr,256,0, wp,256,0, res1,0,256,0,
        bo, h_hi, h_lo, nullptr, nullptr);

    // --- h1 = LN1(res1) (fp16) ---
    ln_kernel<0, _Float16><<<dim3(MTB/4), 256, 0, stream>>>(
        res1, ln1_g, ln1_b, nullptr, nullptr, h1, 0, MTB);

    // --- fused FF: res2 = h1 + relu(h1@W1^T+b1)@W2^T + b2 ---
    cvt_kernel<<<dim3(2048), 256, 0, stream>>>(W1, 256, 8, w1p, 524288);
    cvt_kernel<<<dim3(2048), 256, 0, stream>>>(W2, 2048, 11, w2p, 524288);
    ff_kernel<<<dim3(1024), 256, 0, stream>>>(h1, w1p, w2p, b1, b2, res2);

    // --- q(planes) = h(planes) + LN2(res2) ---
    ln_kernel<1, _Float16><<<dim3(MTB/4), 256, 0, stream>>>(
        res2, ln2_g, ln2_b, h_hi, h_lo, q_hi, PL, MTB);

    // --- e[b][t][i] = q . U_p  (3-pass split-fp16, fp32-class) ---
    gemm_h<0, 3, 0, float, 0, float, 0>
        <<<dim3(2,2,256), 256, 0, stream>>>(
        256,256,256, q_hi,q_lo,65536,256, U_p,65536,256, e,0,256,65536,
        nullptr, (const float*)nullptr, nullptr, nullptr, nullptr);

    // --- masked softmax over i ---
    smax_kernel<<<dim3(MTB/4), 256, 0, stream>>>(e, seqlen);

    // --- r = a @ U_p (fp16 out) ---
    gemm_h<0, 0, 1, _Float16, 0, float, 0>
        <<<dim3(2,2,256), 256, 0, stream>>>(
        256,256,256, e,nullptr,256,65536, U_p,65536,256, r,0,65536,256,
        nullptr, (const float*)nullptr, nullptr, nullptr, nullptr);

    // --- hidden = relu([mask(U_s), r] @ W_fc^T + b_fc) fp16, fused K=512 ---
    cvt_kernel<<<dim3(1024), 256, 0, stream>>>(W_fc, 512, 9, wp, 262144);
    gemm_h<E_BIAS|E_RELU|E_MASKA, 4, 2, _Float16, 0, float, 0>
        <<<dim3(4,512,1), 256, 0, stream>>>(
        MTB,512,512, U_s,r,256,0, wp,512,0, hid,0,512,0,
        b_fc, (const float*)nullptr, nullptr, nullptr, seqlen);

    // --- logits + log_softmax + ragged gather ---
    head_kernel<<<dim3(MTB/4), 256, 0, stream>>>(hid, W_sm, b_sm, seqlen, offs, out);
}

// Round 9
// 924.092 us; speedup vs baseline: 4.4625x; 1.2538x over previous
//
#include <hip/hip_runtime.h>

#define MTB 65536   // T*B rows

typedef unsigned int uint;
typedef unsigned short ushort;

typedef _Float16 h8 __attribute__((ext_vector_type(8)));   // 8 fp16 (4 VGPR)
typedef __attribute__((ext_vector_type(4))) float f4;      // mfma accumulator

enum { E_BIAS=1, E_RELU=2, E_ACC=4, E_RES=8, E_PE=16, E_MASKA=32 };

__device__ __forceinline__ float ldsc(const float* p) { return *p; }
__device__ __forceinline__ float ldsc(const _Float16* p) { return (float)*p; }

// ---------------------------------------------------------------------------
// fp16 MFMA GEMM: C = A @ W^T (+epilogue), 128x128 tile, BK=32.
// AMODE: 0 = A f32 -> cvt fp16 in staging (optional MASKA)
//        2 = A fp16 stored, copy staging
//        3 = A fp16 2-plane stored (Ap hi, Ap2 lo) -> 3 passes (needs BMODE=0)
//        4 = hybrid K=512: k<256 from f32 Ap (masked), k>=256 from fp16 Ap2
// BMODE: 0 = W f32 [N,K] -> split into 2 fp16 planes in staging
//        1 = W f32 [K,N] -> transpose + cvt single fp16
//        2 = W fp16 plane [N,K] (pre-converted), copy staging
// CPL: C written as fp16 hi/lo planes (C + cplane = lo). RPL: res is 2-plane.
// ---------------------------------------------------------------------------
template<int EPI, int AMODE, int BMODE, typename CT, int CPL, typename RT, int RPL>
__global__ __launch_bounds__(256) void gemm_h(
    int M, int N, int K,
    const void* __restrict__ Ap, const void* __restrict__ Ap2, int lda, long batchA,
    const void* __restrict__ Bp, int ldw, long batchW,
    CT* __restrict__ C, long cplane, int ldc, long batchC,
    const float* __restrict__ bias,
    const RT* __restrict__ res, const RT* __restrict__ resLo,
    const float* __restrict__ pe,
    const int* __restrict__ seqlen)
{
    __shared__ _Float16 Ah[128][40];
    __shared__ _Float16 Al[(AMODE==3)?128:1][40];
    __shared__ _Float16 Bh[128][40];
    __shared__ _Float16 Bl[(BMODE==0)?128:1][40];

    const int z = blockIdx.z;
    C += (size_t)z * batchC;
    const float*    Af  = (const float*)Ap + (AMODE==0 ? (size_t)z*batchA : 0);
    const _Float16* Ahp = (const _Float16*)Ap + ((AMODE==2||AMODE==3) ? (size_t)z*batchA : 0);
    const _Float16* Alp = (const _Float16*)Ap2 + (AMODE==3 ? (size_t)z*batchA : 0);
    const float*    Bf  = (const float*)Bp + (BMODE!=2 ? (size_t)z*batchW : 0);
    const _Float16* Bhp = (const _Float16*)Bp;

    const int m0 = blockIdx.y * 128, n0 = blockIdx.x * 128;
    const int tid = threadIdx.x;
    const int lane = tid & 63, wid = tid >> 6;
    const int wr = wid >> 1, wc = wid & 1;

    f4 acc[4][4];
    {
        f4 zr = {0.f, 0.f, 0.f, 0.f};
        #pragma unroll
        for (int i = 0; i < 4; i++)
            #pragma unroll
            for (int j = 0; j < 4; j++) acc[i][j] = zr;
    }

    for (int k0 = 0; k0 < K; k0 += 32) {
        __syncthreads();
        // ---- stage A ----
        if (AMODE == 0 || (AMODE == 4 && k0 < 256)) {
            #pragma unroll
            for (int i = 0; i < 4; i++) {
                const int row = i*32 + (tid>>3);
                const int cg  = (tid&7)<<2;
                const int m = m0 + row;
                float4 v; v.x=0.f; v.y=0.f; v.z=0.f; v.w=0.f;
                bool ok = true;
                if (EPI & E_MASKA) ok = ((m>>8) < seqlen[m&255]);
                if (ok) v = *(const float4*)(Af + (size_t)m*lda + k0 + cg);
                Ah[row][cg+0] = (_Float16)v.x;
                Ah[row][cg+1] = (_Float16)v.y;
                Ah[row][cg+2] = (_Float16)v.z;
                Ah[row][cg+3] = (_Float16)v.w;
            }
        } else if (AMODE == 4) {
            const _Float16* Ar = (const _Float16*)Ap2;
            const int row = tid >> 1;
            const int cg  = (tid & 1) << 4;
            const size_t off = (size_t)(m0 + row) * 256 + (k0 - 256) + cg;
            *(uint4*)&Ah[row][cg]     = *(const uint4*)(Ar + off);
            *(uint4*)&Ah[row][cg + 8] = *(const uint4*)(Ar + off + 8);
        } else {
            const int row = tid >> 1;
            const int cg  = (tid & 1) << 4;
            const size_t off = (size_t)(m0 + row) * lda + k0 + cg;
            *(uint4*)&Ah[row][cg]     = *(const uint4*)(Ahp + off);
            *(uint4*)&Ah[row][cg + 8] = *(const uint4*)(Ahp + off + 8);
            if (AMODE == 3) {
                *(uint4*)&Al[row][cg]     = *(const uint4*)(Alp + off);
                *(uint4*)&Al[row][cg + 8] = *(const uint4*)(Alp + off + 8);
            }
        }
        // ---- stage B ----
        if (BMODE == 2) {
            const int row = tid >> 1;
            const int cg  = (tid & 1) << 4;
            const size_t off = (size_t)(n0 + row) * ldw + k0 + cg;
            *(uint4*)&Bh[row][cg]     = *(const uint4*)(Bhp + off);
            *(uint4*)&Bh[row][cg + 8] = *(const uint4*)(Bhp + off + 8);
        } else if (BMODE == 0) {
            #pragma unroll
            for (int i = 0; i < 4; i++) {
                const int row = i*32 + (tid>>3);
                const int cg  = (tid&7)<<2;
                float4 v = *(const float4*)(Bf + (size_t)(n0+row)*ldw + k0 + cg);
                _Float16 h0 = (_Float16)v.x, h1 = (_Float16)v.y,
                         h2 = (_Float16)v.z, h3 = (_Float16)v.w;
                Bh[row][cg+0]=h0; Bl[row][cg+0]=(_Float16)(v.x-(float)h0);
                Bh[row][cg+1]=h1; Bl[row][cg+1]=(_Float16)(v.y-(float)h1);
                Bh[row][cg+2]=h2; Bl[row][cg+2]=(_Float16)(v.z-(float)h2);
                Bh[row][cg+3]=h3; Bl[row][cg+3]=(_Float16)(v.w-(float)h3);
            }
        } else {  // BMODE == 1 : W f32 [K,N], transpose + cvt
            #pragma unroll
            for (int i = 0; i < 4; i++) {
                const int kr = i*8 + (tid>>5);
                const int ng = (tid&31)<<2;
                float4 v = *(const float4*)(Bf + (size_t)(k0+kr)*ldw + n0 + ng);
                Bh[ng+0][kr] = (_Float16)v.x;
                Bh[ng+1][kr] = (_Float16)v.y;
                Bh[ng+2][kr] = (_Float16)v.z;
                Bh[ng+3][kr] = (_Float16)v.w;
            }
        }
        __syncthreads();
        // ---- fragments + MFMA ----
        const int lr = lane & 15, lk = (lane>>4)<<3;
        h8 ah[4], bh[4];
        #pragma unroll
        for (int i = 0; i < 4; i++) {
            ah[i] = *(const h8*)&Ah[wr*64 + i*16 + lr][lk];
            bh[i] = *(const h8*)&Bh[wc*64 + i*16 + lr][lk];
        }
        #pragma unroll
        for (int mi = 0; mi < 4; mi++)
            #pragma unroll
            for (int ni = 0; ni < 4; ni++)
                acc[mi][ni] = __builtin_amdgcn_mfma_f32_16x16x32_f16(ah[mi], bh[ni], acc[mi][ni], 0, 0, 0);
        if (AMODE == 3) {
            h8 al[4], bl[4];
            #pragma unroll
            for (int i = 0; i < 4; i++) {
                al[i] = *(const h8*)&Al[wr*64 + i*16 + lr][lk];
                bl[i] = *(const h8*)&Bl[wc*64 + i*16 + lr][lk];
            }
            #pragma unroll
            for (int mi = 0; mi < 4; mi++)
                #pragma unroll
                for (int ni = 0; ni < 4; ni++) {
                    acc[mi][ni] = __builtin_amdgcn_mfma_f32_16x16x32_f16(ah[mi], bl[ni], acc[mi][ni], 0, 0, 0);
                    acc[mi][ni] = __builtin_amdgcn_mfma_f32_16x16x32_f16(al[mi], bh[ni], acc[mi][ni], 0, 0, 0);
                }
        }
    }
    // ---- epilogue: C row = 4*(lane>>4)+reg, col = lane&15 ----
    const int colb = n0 + wc*64;
    const int rowb = m0 + wr*64;
    #pragma unroll
    for (int ni = 0; ni < 4; ni++) {
        const int col = colb + ni*16 + (lane & 15);
        float bv = (EPI & E_BIAS) ? bias[col] : 0.f;
        #pragma unroll
        for (int mi = 0; mi < 4; mi++) {
            const int r0 = rowb + mi*16 + ((lane>>4)<<2);
            #pragma unroll
            for (int j = 0; j < 4; j++) {
                const int row = r0 + j;
                const size_t idx = (size_t)row*ldc + col;
                float v = acc[mi][ni][j] + bv;
                if (EPI & E_PE)  v += pe[((row & 255) << 8) + col];
                if (EPI & E_RES) {
                    v += ldsc(res + idx);
                    if (RPL) v += ldsc(resLo + idx);
                }
                CT* cp = C + idx;
                if (EPI & E_ACC) v += ldsc((const CT*)cp);
                if (EPI & E_RELU) v = fmaxf(v, 0.f);
                if (CPL) {
                    _Float16 hh = (_Float16)v;
                    *(_Float16*)cp = hh;
                    *((_Float16*)cp + cplane) = (_Float16)(v - (float)hh);
                } else if (sizeof(CT) == 2) {
                    *(_Float16*)cp = (_Float16)v;
                } else {
                    *(float*)cp = v;
                }
            }
        }
    }
}

// ---------------------------------------------------------------------------
// Fused FF: res2 = h1 + relu(h1 @ W1^T + b1) @ W2^T + b2  (from round 8)
// ---------------------------------------------------------------------------
__global__ __launch_bounds__(256) void ff_kernel(
    const _Float16* __restrict__ h1,
    const _Float16* __restrict__ W1p,
    const _Float16* __restrict__ W2p,
    const float* __restrict__ b1,
    const float* __restrict__ b2,
    float* __restrict__ res2)
{
    __shared__ _Float16 h1t[64][264];
    __shared__ _Float16 zt[64][136];
    __shared__ _Float16 Bs[256][40];
    const int m0 = blockIdx.x * 64;
    const int tid = threadIdx.x;
    const int lane = tid & 63, wid = tid >> 6;
    const int wr = wid >> 1, wc = wid & 1;
    const int lr = lane & 15, lk = (lane >> 4) << 3;
    const int l4 = (lane >> 4) << 2;

    {
        const int row = tid >> 2, c0 = (tid & 3) << 6;
        const _Float16* src = h1 + (size_t)(m0 + row) * 256 + c0;
        #pragma unroll
        for (int j = 0; j < 8; j++)
            *(uint4*)&h1t[row][c0 + 8*j] = *(const uint4*)(src + 8*j);
    }

    f4 acc2[2][8];
    {
        f4 zr = {0.f,0.f,0.f,0.f};
        #pragma unroll
        for (int mi = 0; mi < 2; mi++)
            #pragma unroll
            for (int ni = 0; ni < 8; ni++) acc2[mi][ni] = zr;
    }

    for (int c = 0; c < 16; c++) {
        f4 acc1[2][4];
        {
            f4 zr = {0.f,0.f,0.f,0.f};
            #pragma unroll
            for (int mi = 0; mi < 2; mi++)
                #pragma unroll
                for (int ni = 0; ni < 4; ni++) acc1[mi][ni] = zr;
        }
        for (int k0 = 0; k0 < 256; k0 += 32) {
            __syncthreads();
            {
                const int row = tid >> 1, cc = (tid & 1) << 4;
                const size_t off = (size_t)(c*128 + row) * 256 + k0 + cc;
                *(uint4*)&Bs[row][cc]   = *(const uint4*)(W1p + off);
                *(uint4*)&Bs[row][cc+8] = *(const uint4*)(W1p + off + 8);
            }
            __syncthreads();
            h8 a0 = *(const h8*)&h1t[wr*32 +      lr][k0 + lk];
            h8 a1 = *(const h8*)&h1t[wr*32 + 16 + lr][k0 + lk];
            #pragma unroll
            for (int ni = 0; ni < 4; ni++) {
                const h8 b = *(const h8*)&Bs[wc*64 + ni*16 + lr][lk];
                acc1[0][ni] = __builtin_amdgcn_mfma_f32_16x16x32_f16(a0, b, acc1[0][ni], 0, 0, 0);
                acc1[1][ni] = __builtin_amdgcn_mfma_f32_16x16x32_f16(a1, b, acc1[1][ni], 0, 0, 0);
            }
        }
        #pragma unroll
        for (int ni = 0; ni < 4; ni++) {
            const float bv = b1[c*128 + wc*64 + ni*16 + lr];
            #pragma unroll
            for (int mi = 0; mi < 2; mi++)
                #pragma unroll
                for (int j = 0; j < 4; j++) {
                    float v = acc1[mi][ni][j] + bv;
                    v = fmaxf(v, 0.f);
                    zt[wr*32 + mi*16 + l4 + j][wc*64 + ni*16 + lr] = (_Float16)v;
                }
        }
        __syncthreads();
        for (int kk = 0; kk < 128; kk += 32) {
            if (kk) __syncthreads();
            {
                const size_t off = (size_t)tid * 2048 + c*128 + kk;
                #pragma unroll
                for (int j = 0; j < 4; j++)
                    *(uint4*)&Bs[tid][8*j] = *(const uint4*)(W2p + off + 8*j);
            }
            __syncthreads();
            h8 a0 = *(const h8*)&zt[wr*32 +      lr][kk + lk];
            h8 a1 = *(const h8*)&zt[wr*32 + 16 + lr][kk + lk];
            #pragma unroll
            for (int ni = 0; ni < 8; ni++) {
                const h8 b = *(const h8*)&Bs[wc*128 + ni*16 + lr][lk];
                acc2[0][ni] = __builtin_amdgcn_mfma_f32_16x16x32_f16(a0, b, acc2[0][ni], 0, 0, 0);
                acc2[1][ni] = __builtin_amdgcn_mfma_f32_16x16x32_f16(a1, b, acc2[1][ni], 0, 0, 0);
            }
        }
        __syncthreads();
    }
    #pragma unroll
    for (int ni = 0; ni < 8; ni++) {
        const int col = wc*128 + ni*16 + lr;
        const float bv = b2[col];
        #pragma unroll
        for (int mi = 0; mi < 2; mi++) {
            const int rl = wr*32 + mi*16 + l4;
            #pragma unroll
            for (int j = 0; j < 4; j++) {
                float v = acc2[mi][ni][j] + bv + (float)h1t[rl + j][col];
                res2[(size_t)(m0 + rl + j) * 256 + col] = v;
            }
        }
    }
}

// ---------- f32 -> fp16 plane convert (strided source) ----------
__global__ void cvt_kernel(const float* __restrict__ src, int ld, int cshift,
                           _Float16* __restrict__ dst, int total)
{
    const int i = blockIdx.x * 256 + threadIdx.x;
    if (i >= total) return;
    const int r = i >> cshift, c = i & ((1 << cshift) - 1);
    dst[i] = (_Float16)src[(size_t)r * ld + c];
}

// ---------------------------------------------------------------------------
// MFMA flash attention per (b, head). 4 waves; wave w owns 64 query rows.
// Flash over 4 key-tiles of 64. K LDS [64][68]; V transposed Vt[64][68];
// per-wave P buffer [64][68]. S/O in f32 MFMA accumulators.
// ---------------------------------------------------------------------------
__global__ __launch_bounds__(256) void attn_kernel(const _Float16* __restrict__ qkv,
                                                   _Float16* __restrict__ o)
{
    __shared__ _Float16 Kl[64][68];      // 8.7 KB
    __shared__ _Float16 Vt[64][68];      // 8.7 KB
    __shared__ _Float16 Pl[4][64][68];   // 34.8 KB
    const int b = blockIdx.x, head = blockIdx.y;
    const _Float16* base = qkv + (size_t)b * 768 + head * 64;
    const int tid = threadIdx.x;
    const int lane = tid & 63, wid = tid >> 6;
    const int lr = lane & 15, lg = lane >> 4;     // lg in 0..3
    const int lk = lg << 3;
    const int q0 = wid * 64;

    // Q fragments straight from global (A-layout is 8 contiguous fp16)
    h8 qf[4][2];
    #pragma unroll
    for (int mi = 0; mi < 4; mi++)
        #pragma unroll
        for (int kk = 0; kk < 2; kk++)
            qf[mi][kk] = *(const h8*)(base + (size_t)(q0 + mi*16 + lr) * 196608 + kk*32 + lk);

    f4 oacc[4][4];
    float m_st[4][4], l_st[4][4];
    {
        f4 zr = {0.f,0.f,0.f,0.f};
        #pragma unroll
        for (int mi = 0; mi < 4; mi++)
            #pragma unroll
            for (int di = 0; di < 4; di++) oacc[mi][di] = zr;
        #pragma unroll
        for (int mi = 0; mi < 4; mi++)
            #pragma unroll
            for (int j = 0; j < 4; j++) { m_st[mi][j] = -1e30f; l_st[mi][j] = 0.f; }
    }

    for (int kt = 0; kt < 4; kt++) {
        __syncthreads();
        // stage K tile and transposed V tile
        {
            const int row = tid >> 2, c0 = (tid & 3) << 4;
            const _Float16* rp = base + (size_t)(kt*64 + row) * 196608;
            *(uint4*)&Kl[row][c0]     = *(const uint4*)(rp + 256 + c0);
            *(uint4*)&Kl[row][c0 + 8] = *(const uint4*)(rp + 256 + c0 + 8);
            const h8 v0 = *(const h8*)(rp + 512 + c0);
            const h8 v1 = *(const h8*)(rp + 512 + c0 + 8);
            #pragma unroll
            for (int j = 0; j < 8; j++) {
                Vt[c0 + j][row]     = v0[j];
                Vt[c0 + 8 + j][row] = v1[j];
            }
        }
        __syncthreads();
        // S = 0.125 * Q K^T for this tile
        f4 sacc[4][4];
        {
            f4 zr = {0.f,0.f,0.f,0.f};
            #pragma unroll
            for (int mi = 0; mi < 4; mi++)
                #pragma unroll
                for (int ni = 0; ni < 4; ni++) sacc[mi][ni] = zr;
        }
        #pragma unroll
        for (int kk = 0; kk < 2; kk++) {
            h8 kf[4];
            #pragma unroll
            for (int ni = 0; ni < 4; ni++)
                kf[ni] = *(const h8*)&Kl[ni*16 + lr][kk*32 + lk];
            #pragma unroll
            for (int mi = 0; mi < 4; mi++)
                #pragma unroll
                for (int ni = 0; ni < 4; ni++)
                    sacc[mi][ni] = __builtin_amdgcn_mfma_f32_16x16x32_f16(qf[mi][kk], kf[ni], sacc[mi][ni], 0, 0, 0);
        }
        #pragma unroll
        for (int mi = 0; mi < 4; mi++)
            #pragma unroll
            for (int ni = 0; ni < 4; ni++)
                #pragma unroll
                for (int j = 0; j < 4; j++) sacc[mi][ni][j] *= 0.125f;
        // row-wise flash update; row r = mi*16 + 4*lg + j lives in 16 lanes (lr)
        #pragma unroll
        for (int mi = 0; mi < 4; mi++) {
            #pragma unroll
            for (int j = 0; j < 4; j++) {
                float tm = fmaxf(fmaxf(sacc[mi][0][j], sacc[mi][1][j]),
                                 fmaxf(sacc[mi][2][j], sacc[mi][3][j]));
                tm = fmaxf(tm, __shfl_xor(tm, 1));
                tm = fmaxf(tm, __shfl_xor(tm, 2));
                tm = fmaxf(tm, __shfl_xor(tm, 4));
                tm = fmaxf(tm, __shfl_xor(tm, 8));
                const float mn = fmaxf(m_st[mi][j], tm);
                const float sc = __expf(m_st[mi][j] - mn);
                m_st[mi][j] = mn;
                float ps = 0.f;
                #pragma unroll
                for (int ni = 0; ni < 4; ni++) {
                    const float p = __expf(sacc[mi][ni][j] - mn);
                    sacc[mi][ni][j] = p;
                    ps += p;
                }
                ps += __shfl_xor(ps, 1);
                ps += __shfl_xor(ps, 2);
                ps += __shfl_xor(ps, 4);
                ps += __shfl_xor(ps, 8);
                l_st[mi][j] = l_st[mi][j] * sc + ps;
                #pragma unroll
                for (int di = 0; di < 4; di++) oacc[mi][di][j] *= sc;
            }
        }
        // write P (fp16) to per-wave LDS: C-layout -> A-layout
        #pragma unroll
        for (int mi = 0; mi < 4; mi++)
            #pragma unroll
            for (int ni = 0; ni < 4; ni++)
                #pragma unroll
                for (int j = 0; j < 4; j++)
                    Pl[wid][mi*16 + (lg<<2) + j][ni*16 + lr] = (_Float16)sacc[mi][ni][j];
        // O += P @ Vt^T
        #pragma unroll
        for (int kk = 0; kk < 2; kk++) {
            h8 pf[4], vf[4];
            #pragma unroll
            for (int mi = 0; mi < 4; mi++)
                pf[mi] = *(const h8*)&Pl[wid][mi*16 + lr][kk*32 + lk];
            #pragma unroll
            for (int di = 0; di < 4; di++)
                vf[di] = *(const h8*)&Vt[di*16 + lr][kk*32 + lk];
            #pragma unroll
            for (int mi = 0; mi < 4; mi++)
                #pragma unroll
                for (int di = 0; di < 4; di++)
                    oacc[mi][di] = __builtin_amdgcn_mfma_f32_16x16x32_f16(pf[mi], vf[di], oacc[mi][di], 0, 0, 0);
        }
    }
    // O /= l; write out (o layout [T,B,256])
    _Float16* obase = o + (size_t)b * 256 + head * 64;
    #pragma unroll
    for (int mi = 0; mi < 4; mi++) {
        #pragma unroll
        for (int j = 0; j < 4; j++) {
            const float inv = 1.f / l_st[mi][j];
            const size_t rowoff = (size_t)(q0 + mi*16 + (lg<<2) + j) * 65536;
            #pragma unroll
            for (int di = 0; di < 4; di++)
                obase[rowoff + di*16 + lr] = (_Float16)(oacc[mi][di][j] * inv);
        }
    }
}

// ---------- LayerNorm; optional fp16-plane addin; f32 or fp16(/plane) out ----------
template<int OPL, typename OT>
__global__ __launch_bounds__(256) void ln_kernel(const float* __restrict__ x,
    const float* __restrict__ g, const float* __restrict__ bt,
    const _Float16* __restrict__ addin, const _Float16* __restrict__ addinLo,
    OT* __restrict__ out, long oplane, int nrows)
{
    const int gid = blockIdx.x * 256 + threadIdx.x;
    const int row = gid >> 6;
    const int lane = threadIdx.x & 63;
    if (row >= nrows) return;
    const float* xr = x + (size_t)row * 256;
    float4 v = *(const float4*)(xr + (lane<<2));
    float s = v.x + v.y + v.z + v.w;
    #pragma unroll
    for (int off = 32; off > 0; off >>= 1) s += __shfl_xor(s, off, 64);
    const float mean = s * (1.0f/256.0f);
    const float dx = v.x-mean, dy = v.y-mean, dz = v.z-mean, dw = v.w-mean;
    float ss = dx*dx + dy*dy + dz*dz + dw*dw;
    #pragma unroll
    for (int off = 32; off > 0; off >>= 1) ss += __shfl_xor(ss, off, 64);
    const float inv = rsqrtf(ss * (1.0f/256.0f) + 1e-5f);
    const float4 gv = *(const float4*)(g + (lane<<2));
    const float4 bv = *(const float4*)(bt + (lane<<2));
    float ov[4];
    ov[0] = dx*inv*gv.x + bv.x;
    ov[1] = dy*inv*gv.y + bv.y;
    ov[2] = dz*inv*gv.z + bv.z;
    ov[3] = dw*inv*gv.w + bv.w;
    const size_t base = (size_t)row*256 + (lane<<2);
    if (addin) {
        #pragma unroll
        for (int j = 0; j < 4; j++) {
            ov[j] += (float)addin[base+j];
            if (addinLo) ov[j] += (float)addinLo[base+j];
        }
    }
    #pragma unroll
    for (int j = 0; j < 4; j++) {
        if (OPL) {
            _Float16 hh = (_Float16)ov[j];
            ((_Float16*)out)[base+j] = hh;
            ((_Float16*)out)[base+j+oplane] = (_Float16)(ov[j] - (float)hh);
        } else if (sizeof(OT) == 2) {
            ((_Float16*)out)[base+j] = (_Float16)ov[j];
        } else {
            ((float*)out)[base+j] = ov[j];
        }
    }
}

// ---------- masked softmax over i for e[b][t][i], in place, fp32 ----------
__global__ __launch_bounds__(256) void smax_kernel(float* __restrict__ e,
                                                   const int* __restrict__ seqlen)
{
    const int gid = blockIdx.x * 256 + threadIdx.x;
    const int row = gid >> 6;               // row = b*256 + t
    const int lane = threadIdx.x & 63;
    const int L = seqlen[row >> 8];
    float* er = e + (size_t)row * 256;
    float4 v = *(const float4*)(er + (lane<<2));
    const int i0 = lane << 2;
    const float x0 = (i0+0 < L) ? v.x : -1e30f;
    const float x1 = (i0+1 < L) ? v.y : -1e30f;
    const float x2 = (i0+2 < L) ? v.z : -1e30f;
    const float x3 = (i0+3 < L) ? v.w : -1e30f;
    float mx = fmaxf(fmaxf(x0,x1), fmaxf(x2,x3));
    #pragma unroll
    for (int off = 32; off > 0; off >>= 1) mx = fmaxf(mx, __shfl_xor(mx, off, 64));
    const float p0 = (i0+0 < L) ? __expf(x0-mx) : 0.f;
    const float p1 = (i0+1 < L) ? __expf(x1-mx) : 0.f;
    const float p2 = (i0+2 < L) ? __expf(x2-mx) : 0.f;
    const float p3 = (i0+3 < L) ? __expf(x3-mx) : 0.f;
    float s = p0+p1+p2+p3;
    #pragma unroll
    for (int off = 32; off > 0; off >>= 1) s += __shfl_xor(s, off, 64);
    const float inv = 1.f / s;
    v.x = p0*inv; v.y = p1*inv; v.z = p2*inv; v.w = p3*inv;
    *(float4*)(er + (lane<<2)) = v;
}

// ---------- head: logits (512->7) + log_softmax + ragged scatter; hid fp16 ----------
__global__ __launch_bounds__(256) void head_kernel(const _Float16* __restrict__ hidden,
    const float* __restrict__ Wsm, const float* __restrict__ bsm,
    const int* __restrict__ seqlen, const int* __restrict__ offs,
    float* __restrict__ out)
{
    const int gid = blockIdx.x * 256 + threadIdx.x;
    const int row = gid >> 6;
    const int lane = threadIdx.x & 63;
    if (row >= MTB) return;
    const int t = row >> 8, b = row & 255;
    if (t >= seqlen[b]) return;
    const _Float16* hr = hidden + (size_t)row * 512;
    const h8 hu = *(const h8*)(hr + lane*8);
    float hv[8];
    #pragma unroll
    for (int j = 0; j < 8; j++) hv[j] = (float)hu[j];
    float lg[7];
    #pragma unroll
    for (int c = 0; c < 7; c++) {
        const float* wr = Wsm + c*512 + lane*8;
        const float4 w0 = *(const float4*)wr;
        const float4 w1 = *(const float4*)(wr + 4);
        float acc = hv[0]*w0.x + hv[1]*w0.y + hv[2]*w0.z + hv[3]*w0.w
                  + hv[4]*w1.x + hv[5]*w1.y + hv[6]*w1.z + hv[7]*w1.w;
        #pragma unroll
        for (int off = 32; off > 0; off >>= 1) acc += __shfl_xor(acc, off, 64);
        lg[c] = acc + bsm[c];
    }
    float mx = lg[0];
    #pragma unroll
    for (int c = 1; c < 7; c++) mx = fmaxf(mx, lg[c]);
    float s = 0.f;
    #pragma unroll
    for (int c = 0; c < 7; c++) s += __expf(lg[c] - mx);
    const float lse = mx + logf(s);
    if (lane == 0) {
        float* orow = out + (size_t)(offs[b] + t) * 7;
        #pragma unroll
        for (int c = 0; c < 7; c++) orow[c] = lg[c] - lse;
    }
}

// ---------- positional encoding over the BATCH dim (faithful quirk) ----------
__global__ void pe_kernel(float* __restrict__ pe)
{
    const int idx = blockIdx.x * 256 + threadIdx.x;   // 65536 = 256x256
    const int b = idx >> 8, f = idx & 255;
    const int j = f >> 1;
    const float div = expf(-9.210340371976184f * (2.0f * j) * (1.0f/256.0f));
    const float arg = (float)b * div;
    pe[idx] = (f & 1) ? cosf(arg) : sinf(arg);
}

// ---------- exclusive prefix sum of seq lengths ----------
__global__ void prefix_kernel(const int* __restrict__ L, int* __restrict__ offs)
{
    if (threadIdx.x == 0) {
        int acc = 0;
        for (int i = 0; i < 256; i++) { offs[i] = acc; acc += L[i]; }
        offs[256] = acc;
    }
}

// ---------- diagnostic: report ws_size via absmax if insufficient ----------
__global__ void sentinel_kernel(float* __restrict__ out, float v)
{
    if (threadIdx.x == 0) out[0] = v;
}

// ---------------------------------------------------------------------------
extern "C" void kernel_launch(void* const* d_in, const int* in_sizes, int n_in,
                              void* d_out, int out_size, void* d_ws, size_t ws_size,
                              hipStream_t stream)
{
    const float* U_s   = (const float*)d_in[0];
    const float* U_p   = (const float*)d_in[1];
    const float* W_emb = (const float*)d_in[2];
    const float* b_emb = (const float*)d_in[3];
    const float* Wqkv  = (const float*)d_in[4];
    const float* bqkv  = (const float*)d_in[5];
    const float* Wo    = (const float*)d_in[6];
    const float* bo    = (const float*)d_in[7];
    const float* ln1_g = (const float*)d_in[8];
    const float* ln1_b = (const float*)d_in[9];
    const float* W1    = (const float*)d_in[10];
    const float* b1    = (const float*)d_in[11];
    const float* W2    = (const float*)d_in[12];
    const float* b2    = (const float*)d_in[13];
    const float* ln2_g = (const float*)d_in[14];
    const float* ln2_b = (const float*)d_in[15];
    const float* W_fc  = (const float*)d_in[16];
    const float* b_fc  = (const float*)d_in[17];
    const float* W_sm  = (const float*)d_in[18];
    const float* b_sm  = (const float*)d_in[19];
    const int*   seqlen= (const int*)d_in[20];
    float* out = (float*)d_out;

    // ---- aliased workspace arena, peak 193 MiB ----
    const size_t MiB = 1024*1024;
    const size_t KiB = 1024;
    char* ws = (char*)d_ws;
    if (ws_size < 193*MiB) {
        sentinel_kernel<<<dim3(1), dim3(64), 0, stream>>>(out, -(float)(ws_size / MiB));
        return;
    }
    const long PL = 16*1024*1024;                        // plane stride (elems)
    _Float16* h_hi = (_Float16*)(ws);                    // [0,32M)
    _Float16* h_lo = (_Float16*)(ws + 32*MiB);           // [32,64M)
    int*      offs = (int*)(ws + 64*MiB);                // 4 KiB
    char*     slot = ws + 64*MiB + 8*KiB;                // <1 MiB weight slot
    _Float16* qkv  = (_Float16*)(ws + 65*MiB);           // [65,161M), dead after attn
    _Float16* o    = (_Float16*)(ws + 161*MiB);          // [161,193M), dead after proj
    float*    res1 = (float*)(ws + 65*MiB);              // [65,129M) f32 (over dead qkv)
    float*    res2 = res1;
    _Float16* h1   = (_Float16*)(ws + 161*MiB);          // [161,193M) (over dead o)
    _Float16* w1p  = (_Float16*)(ws + 129*MiB);          // [129,130M) FF weights (fp16)
    _Float16* w2p  = (_Float16*)(ws + 130*MiB);          // [130,131M)
    _Float16* q_hi = (_Float16*)(ws + 129*MiB);          // [129,161M) (over dead w1p/w2p)
    _Float16* q_lo = (_Float16*)(ws + 161*MiB);          // [161,193M) (over dead h1)
    float*    e    = (float*)(ws + 65*MiB);              // [65,129M)  (over dead res2)
    _Float16* r    = (_Float16*)(ws);                    // [0,32M)    (over dead h planes)
    _Float16* hid  = (_Float16*)(ws + 129*MiB);          // [129,193M) (over dead q planes)

    prefix_kernel<<<dim3(1), dim3(64), 0, stream>>>(seqlen, offs);

    _Float16* wp  = (_Float16*)slot;                     // rotating weight plane
    float*    pe  = (float*)(slot + 512*KiB);            // 256 KiB, embed only

    // --- embed: h(planes) = mask(U_s) @ W_emb^T + b_emb + pe[b,:] ---
    cvt_kernel<<<dim3(256), 256, 0, stream>>>(W_emb, 256, 8, wp, 65536);
    pe_kernel<<<dim3(256), dim3(256), 0, stream>>>(pe);
    gemm_h<E_BIAS|E_PE|E_MASKA, 0, 2, _Float16, 1, float, 0>
        <<<dim3(2,512,1), 256, 0, stream>>>(
        MTB,256,256, U_s,nullptr,256,0, wp,256,0, h_hi,PL,256,0,
        b_emb, (const float*)nullptr, nullptr, pe, seqlen);

    // --- qkv = h @ Wqkv^T + bqkv (fp16) ---
    cvt_kernel<<<dim3(768), 256, 0, stream>>>(Wqkv, 256, 8, wp, 196608);
    gemm_h<E_BIAS, 2, 2, _Float16, 0, float, 0>
        <<<dim3(6,512,1), 256, 0, stream>>>(
        MTB,768,256, h_hi,nullptr,256,0, wp,256,0, qkv,0,768,0,
        bqkv, (const float*)nullptr, nullptr, nullptr, nullptr);

    // --- MFMA flash attention -> o [T,B,256] fp16 ---
    attn_kernel<<<dim3(256,4), 256, 0, stream>>>(qkv, o);

    // --- res1 = o @ Wo^T + bo + h(planes) ---
    cvt_kernel<<<dim3(256), 256, 0, stream>>>(Wo, 256, 8, wp, 65536);
    gemm_h<E_BIAS|E_RES, 2, 2, float, 0, _Float16, 1>
        <<<dim3(2,512,1), 256, 0, stream>>>(
        MTB,256,256, o,nullptr,256,0, wp,256,0, res1,0,256,0,
        bo, h_hi, h_lo, nullptr, nullptr);

    // --- h1 = LN1(res1) (fp16) ---
    ln_kernel<0, _Float16><<<dim3(MTB/4), 256, 0, stream>>>(
        res1, ln1_g, ln1_b, nullptr, nullptr, h1, 0, MTB);

    // --- fused FF: res2 = h1 + relu(h1@W1^T+b1)@W2^T + b2 ---
    cvt_kernel<<<dim3(2048), 256, 0, stream>>>(W1, 256, 8, w1p, 524288);
    cvt_kernel<<<dim3(2048), 256, 0, stream>>>(W2, 2048, 11, w2p, 524288);
    ff_kernel<<<dim3(1024), 256, 0, stream>>>(h1, w1p, w2p, b1, b2, res2);

    // --- q(planes) = h(planes) + LN2(res2) ---
    ln_kernel<1, _Float16><<<dim3(MTB/4), 256, 0, stream>>>(
        res2, ln2_g, ln2_b, h_hi, h_lo, q_hi, PL, MTB);

    // --- e[b][t][i] = q . U_p  (3-pass split-fp16, fp32-class) ---
    gemm_h<0, 3, 0, float, 0, float, 0>
        <<<dim3(2,2,256), 256, 0, stream>>>(
        256,256,256, q_hi,q_lo,65536,256, U_p,65536,256, e,0,256,65536,
        nullptr, (const float*)nullptr, nullptr, nullptr, nullptr);

    // --- masked softmax over i ---
    smax_kernel<<<dim3(MTB/4), 256, 0, stream>>>(e, seqlen);

    // --- r = a @ U_p (fp16 out) ---
    gemm_h<0, 0, 1, _Float16, 0, float, 0>
        <<<dim3(2,2,256), 256, 0, stream>>>(
        256,256,256, e,nullptr,256,65536, U_p,65536,256, r,0,65536,256,
        nullptr, (const float*)nullptr, nullptr, nullptr, nullptr);

    // --- hidden = relu([mask(U_s), r] @ W_fc^T + b_fc) fp16, fused K=512 ---
    cvt_kernel<<<dim3(1024), 256, 0, stream>>>(W_fc, 512, 9, wp, 262144);
    gemm_h<E_BIAS|E_RELU|E_MASKA, 4, 2, _Float16, 0, float, 0>
        <<<dim3(4,512,1), 256, 0, stream>>>(
        MTB,512,512, U_s,r,256,0, wp,512,0, hid,0,512,0,
        b_fc, (const float*)nullptr, nullptr, nullptr, seqlen);

    // --- logits + log_softmax + ragged gather ---
    head_kernel<<<dim3(MTB/4), 256, 0, stream>>>(hid, W_sm, b_sm, seqlen, offs, out);
}